// Round 2
// baseline (1342.792 us; speedup 1.0000x reference)
//
#include <hip/hip_runtime.h>
#include <hip/hip_bf16.h>

typedef __hip_bfloat16 bf16;

#define Nn   50000
#define Ee   800000
#define E2   850000
#define Bb   128
#define NFd  7
#define HID  128
#define OUTD 64
#define EPS  1e-5f
#define SLOPE 0.2f

__device__ __forceinline__ float lane_bcast(float v, int l){
  return __int_as_float(__builtin_amdgcn_readlane(__float_as_int(v), l));
}
__device__ __forceinline__ float wred_sum(float v){
  #pragma unroll
  for (int o=32;o;o>>=1) v += __shfl_xor(v, o, 64);
  return v;
}
__device__ __forceinline__ float gred16_sum(float v){
  v += __shfl_xor(v,1,64); v += __shfl_xor(v,2,64);
  v += __shfl_xor(v,4,64); v += __shfl_xor(v,8,64);
  return v;
}
__device__ __forceinline__ unsigned fkey(float f){
  unsigned u = __float_as_uint(f);
  return (u & 0x80000000u) ? ~u : (u | 0x80000000u);
}
__device__ __forceinline__ float fkeyinv(unsigned k){
  unsigned u = (k & 0x80000000u) ? (k ^ 0x80000000u) : ~k;
  return __uint_as_float(u);
}
__device__ __forceinline__ float tanh_fast(float x){
  float e = __expf(fminf(fmaxf(2.f*x, -30.f), 30.f));
  return (e-1.f)/(e+1.f);
}
__device__ __forceinline__ float bf_lo(unsigned u){ return __uint_as_float(u<<16); }
__device__ __forceinline__ float bf_hi(unsigned u){ return __uint_as_float(u & 0xffff0000u); }
__device__ __forceinline__ unsigned short f2bs(float f){
  bf16 h = __float2bfloat16(f);
  return *reinterpret_cast<unsigned short*>(&h);
}

// ---------------- encoder: h = LN(ReLU(x @ W + b)) ----------------
__global__ __launch_bounds__(256) void k_encoder(
    const float* __restrict__ x, const float* __restrict__ W, const float* __restrict__ b,
    const float* __restrict__ g, const float* __restrict__ bbv, float* __restrict__ h){
  int wv = (blockIdx.x*blockDim.x + threadIdx.x) >> 6;
  if (wv >= Nn) return;
  int lane = threadIdx.x & 63;
  int d0 = 2*lane, d1 = d0+1;
  float y0 = b[d0], y1 = b[d1];
  #pragma unroll
  for (int i=0;i<NFd;++i){
    float xv = x[wv*NFd + i];
    y0 = fmaf(xv, W[i*HID + d0], y0);
    y1 = fmaf(xv, W[i*HID + d1], y1);
  }
  y0 = fmaxf(y0, 0.f); y1 = fmaxf(y1, 0.f);
  float mu = wred_sum(y0+y1) * (1.f/HID);
  float c0 = y0-mu, c1 = y1-mu;
  float var = wred_sum(c0*c0 + c1*c1) * (1.f/HID);
  float rs = rsqrtf(var + EPS);
  h[(size_t)wv*HID + d0] = g[d0]*c0*rs + bbv[d0];
  h[(size_t)wv*HID + d1] = g[d1]*c1*rs + bbv[d1];
}

// ---------------- mean of edge_attr ----------------
__global__ void k_ea_mean(const float* __restrict__ ea, float* __restrict__ eam){
  int tid = blockIdx.x*blockDim.x + threadIdx.x;
  const float2* ea2 = (const float2*)ea;
  float a0=0.f, a1=0.f;
  for (int e=tid; e<Ee; e += gridDim.x*blockDim.x){
    float2 v = ea2[e];
    a0 += v.x; a1 += v.y;
  }
  a0 = wred_sum(a0); a1 = wred_sum(a1);
  if ((threadIdx.x & 63)==0){
    atomicAdd(&eam[0], a0*(1.f/Ee));
    atomicAdd(&eam[1], a1*(1.f/Ee));
  }
}

// ---------------- CSR build ----------------
__global__ void k_deg(const int* __restrict__ ei, int* __restrict__ deg){
  int e = blockIdx.x*blockDim.x + threadIdx.x;
  if (e >= E2) return;
  int d = (e < Ee) ? ei[Ee + e] : (e - Ee);
  atomicAdd(&deg[d], 1);
}

__global__ __launch_bounds__(1024) void k_scan(const int* __restrict__ deg,
    int* __restrict__ offs, int* __restrict__ cursor){
  __shared__ int wsum[16];
  __shared__ int tot_s;
  __shared__ int carry_s;
  int t = threadIdx.x, lane = t & 63, wid = t >> 6;
  if (t==0) carry_s = 0;
  __syncthreads();
  for (int base=0; base<Nn; base += 1024){
    int i = base + t;
    int v = (i < Nn) ? deg[i] : 0;
    int x = v;
    #pragma unroll
    for (int o=1;o<64;o<<=1){ int u = __shfl_up(x, o, 64); if (lane >= o) x += u; }
    if (lane==63) wsum[wid] = x;
    __syncthreads();
    if (t==0){ int s=0; for (int k=0;k<16;++k){ int tv=wsum[k]; wsum[k]=s; s+=tv; } tot_s = s; }
    __syncthreads();
    int excl = carry_s + wsum[wid] + x - v;
    if (i < Nn){ offs[i] = excl; cursor[i] = excl; }
    __syncthreads();
    if (t==0) carry_s += tot_s;
    __syncthreads();
  }
  if (t==0) offs[Nn] = carry_s;
}

__global__ void k_scatter(const int* __restrict__ ei, const float* __restrict__ ea,
    const float* __restrict__ eam, int* __restrict__ cursor,
    int* __restrict__ csrc, float2* __restrict__ cea){
  int e = blockIdx.x*blockDim.x + threadIdx.x;
  if (e >= E2) return;
  int s, d; float a0, a1;
  if (e < Ee){
    s = ei[e]; d = ei[Ee + e];
    float2 v = ((const float2*)ea)[e];
    a0 = v.x; a1 = v.y;
  } else {
    s = d = e - Ee; a0 = eam[0]; a1 = eam[1];
  }
  int pos = atomicAdd(&cursor[d], 1);
  csrc[pos] = s;
  cea[pos] = make_float2(a0, a1);
}

// ---------------- per-graph node ranges (batch is sorted) ----------------
__global__ void k_gstart(const int* __restrict__ batch, int* __restrict__ gstart){
  int n = blockIdx.x*blockDim.x + threadIdx.x;
  if (n >= Nn) return;
  int bc = batch[n];
  int bp = (n==0) ? -1 : batch[n-1];
  for (int b = bp+1; b <= bc; ++b) gstart[b] = n;
  if (n == Nn-1){ for (int b = bc+1; b <= Bb; ++b) gstart[b] = Nn; }
}

// ---------------- hs = h@Wsrc, hd = h@Wdst (W->bf16 in LDS, readlane bcast) --
__global__ __launch_bounds__(256) void k_dualgemm(const float* __restrict__ h,
    const float* __restrict__ Wsrc, const float* __restrict__ Wdst,
    float* __restrict__ hs, float* __restrict__ hd){
  __shared__ unsigned short wlds[HID*256];  // 64 KiB: [row i][col c], c<128 -> Wsrc, else Wdst
  for (int idx = threadIdx.x; idx < HID*256/4; idx += 256){
    int r  = idx >> 6;
    int c4 = (idx & 63) * 4;
    const float* sp = (c4 < 128) ? (Wsrc + r*HID + c4) : (Wdst + r*HID + (c4-128));
    float4 v = *(const float4*)sp;
    ushort4 u;
    u.x = f2bs(v.x); u.y = f2bs(v.y); u.z = f2bs(v.z); u.w = f2bs(v.w);
    *(ushort4*)(wlds + r*256 + c4) = u;
  }
  __syncthreads();
  int wid = threadIdx.x >> 6, lane = threadIdx.x & 63;
  int nwaves = gridDim.x * 4;
  for (int p = blockIdx.x*4 + wid; p < Nn/2; p += nwaves){
    int n0 = 2*p, n1 = 2*p + 1;
    float2 h0 = *(const float2*)(h + (size_t)n0*HID + 2*lane);
    float2 h1 = *(const float2*)(h + (size_t)n1*HID + 2*lane);
    float a00=0,a01=0,a02=0,a03=0, a10=0,a11=0,a12=0,a13=0;
    #pragma unroll 8
    for (int i=0;i<HID;++i){
      float hv0 = lane_bcast((i&1) ? h0.y : h0.x, i>>1);
      float hv1 = lane_bcast((i&1) ? h1.y : h1.x, i>>1);
      uint2 wv = *(const uint2*)(wlds + i*256 + 4*lane);
      float w0=bf_lo(wv.x), w1=bf_hi(wv.x), w2=bf_lo(wv.y), w3=bf_hi(wv.y);
      a00=fmaf(hv0,w0,a00); a01=fmaf(hv0,w1,a01); a02=fmaf(hv0,w2,a02); a03=fmaf(hv0,w3,a03);
      a10=fmaf(hv1,w0,a10); a11=fmaf(hv1,w1,a11); a12=fmaf(hv1,w2,a12); a13=fmaf(hv1,w3,a13);
    }
    float* dst0 = (lane < 32) ? (hs + (size_t)n0*HID + 4*lane) : (hd + (size_t)n0*HID + 4*lane - 128);
    float* dst1 = (lane < 32) ? (hs + (size_t)n1*HID + 4*lane) : (hd + (size_t)n1*HID + 4*lane - 128);
    *(float4*)dst0 = make_float4(a00,a01,a02,a03);
    *(float4*)dst1 = make_float4(a10,a11,a12,a13);
  }
}

// ---------------- GATv2 edge aggregation: wave per dst node, online softmax -
__global__ __launch_bounds__(256) void k_edge(const float* __restrict__ hs,
    float* __restrict__ hdio, const float* __restrict__ h,
    const int* __restrict__ csrc, const float2* __restrict__ cea,
    const int* __restrict__ offs, const float* __restrict__ We,
    const float* __restrict__ att, const float* __restrict__ bias){
  int n = (blockIdx.x*blockDim.x + threadIdx.x) >> 6;
  if (n >= Nn) return;
  int lane = threadIdx.x & 63;
  int d0 = 2*lane, d1 = d0+1;
  float we00 = We[d0],       we01 = We[d1];
  float we10 = We[HID+d0],   we11 = We[HID+d1];
  float at0  = att[(lane>>4)*32 + (d0&31)];
  float at1  = att[(lane>>4)*32 + (d1&31)];
  float2 xr = *(const float2*)(hdio + (size_t)n*HID + d0);
  int e0 = offs[n], e1 = offs[n+1];
  float m = -1e30f, ssum = 0.f, acc0 = 0.f, acc1 = 0.f;
  int s_next = csrc[e0];
  float2 ea_next = cea[e0];
  for (int e = e0; e < e1; ++e){
    int s = s_next; float2 eav = ea_next;
    if (e+1 < e1){ s_next = csrc[e+1]; ea_next = cea[e+1]; }
    float2 xl = *(const float2*)(hs + (size_t)s*HID + d0);
    float z0 = xl.x + xr.x + eav.x*we00 + eav.y*we10;
    float z1 = xl.y + xr.y + eav.x*we01 + eav.y*we11;
    z0 = (z0 > 0.f) ? z0 : SLOPE*z0;
    z1 = (z1 > 0.f) ? z1 : SLOPE*z1;
    float sc = gred16_sum(z0*at0 + z1*at1);   // per-head (16-lane group) score
    float nm = fmaxf(m, sc);
    float f  = __expf(m - nm);
    float p  = __expf(sc - nm);
    ssum = ssum*f + p;
    acc0 = acc0*f + p*xl.x;
    acc1 = acc1*f + p*xl.y;
    m = nm;
  }
  float inv = 1.f/ssum;  // every node has its self-loop -> ssum > 0
  float o0 = acc0*inv + bias[d0] + h[(size_t)n*HID + d0];
  float o1 = acc1*inv + bias[d1] + h[(size_t)n*HID + d1];
  *(float2*)(hdio + (size_t)n*HID + d0) = make_float2(o0, o1);
}

// ---------------- GraphNorm + ELU, one block per graph ----------------
__global__ __launch_bounds__(256) void k_gnorm(const float* __restrict__ out,
    float* __restrict__ h, const int* __restrict__ gstart,
    const float* __restrict__ gw, const float* __restrict__ gb,
    const float* __restrict__ gs, float* __restrict__ emb){
  int b = blockIdx.x;
  int ns = gstart[b], ne = gstart[b+1];
  int d = threadIdx.x & 127, half = threadIdx.x >> 7;
  __shared__ float tmp[256];
  __shared__ float mean_s[HID], var_s[HID];
  float cnt = fmaxf((float)(ne-ns), 1.f);
  float acc = 0.f;
  for (int n = ns+half; n < ne; n += 2) acc += out[(size_t)n*HID + d];
  tmp[threadIdx.x] = acc; __syncthreads();
  if (half==0) mean_s[d] = (tmp[d] + tmp[d+128]) / cnt;
  __syncthreads();
  float mn = mean_s[d] * gs[d];   // xc = x - scale*mean
  acc = 0.f;
  for (int n = ns+half; n < ne; n += 2){
    float xc = out[(size_t)n*HID + d] - mn; acc += xc*xc;
  }
  tmp[threadIdx.x] = acc; __syncthreads();
  if (half==0) var_s[d] = (tmp[d] + tmp[d+128]) / cnt;
  __syncthreads();
  float wv = gw[d], bv = gb[d];
  float rs = rsqrtf(var_s[d] + EPS);
  for (int n = ns+half; n < ne; n += 2){
    float xc = out[(size_t)n*HID + d] - mn;
    float y  = wv*xc*rs + bv;
    y = (y > 0.f) ? y : (__expf(y) - 1.f);   // ELU
    h[(size_t)n*HID + d] = y;
    if (emb) emb[(size_t)n*HID + d] = y;
  }
}

// ---------------- pooling scores + global max ----------------
__global__ __launch_bounds__(256) void k_pool_score(const float* __restrict__ h,
    const float* __restrict__ W1, const float* __restrict__ b1, const float* __restrict__ W2,
    float* __restrict__ score, unsigned* __restrict__ mkey){
  __shared__ unsigned short wlds[HID*HID];  // 32 KiB
  for (int idx = threadIdx.x; idx < HID*HID/4; idx += 256){
    float4 v = ((const float4*)W1)[idx];
    ushort4 u;
    u.x = f2bs(v.x); u.y = f2bs(v.y); u.z = f2bs(v.z); u.w = f2bs(v.w);
    ((ushort4*)wlds)[idx] = u;
  }
  __syncthreads();
  int lane = threadIdx.x & 63, wid = threadIdx.x >> 6;
  int d0 = 2*lane, d1 = d0+1;
  float bmax = -1e30f;
  for (int n = blockIdx.x*4 + wid; n < Nn; n += gridDim.x*4){
    float2 hr = *(const float2*)(h + (size_t)n*HID + d0);
    float a0 = b1[d0], a1 = b1[d1];
    #pragma unroll 8
    for (int i=0;i<HID;++i){
      float hv = lane_bcast((i&1) ? hr.y : hr.x, i>>1);
      unsigned wv = *(const unsigned*)(wlds + i*HID + d0);
      a0 = fmaf(hv, bf_lo(wv), a0);
      a1 = fmaf(hv, bf_hi(wv), a1);
    }
    float sc = tanh_fast(a0)*W2[d0] + tanh_fast(a1)*W2[d1];
    sc = wred_sum(sc);
    if (lane==0) score[n] = sc;
    bmax = fmaxf(bmax, sc);
  }
  __shared__ float bm[4];
  if (lane==0) bm[wid] = bmax;
  __syncthreads();
  if (threadIdx.x==0){
    float v = fmaxf(fmaxf(bm[0],bm[1]), fmaxf(bm[2],bm[3]));
    atomicMax(mkey, fkey(v));
  }
}

// ---------------- pooled accumulation per graph ----------------
__global__ __launch_bounds__(256) void k_pool_acc(const float* __restrict__ h,
    const float* __restrict__ score, const unsigned* __restrict__ mkey,
    const int* __restrict__ gstart, float* __restrict__ gsum, float* __restrict__ total){
  int b = blockIdx.x;
  int ns = gstart[b], ne = gstart[b+1];
  float mx = fkeyinv(*mkey);
  int d = threadIdx.x & 127, half = threadIdx.x >> 7;
  float acc = 0.f, esum = 0.f;
  for (int n = ns+half; n < ne; n += 2){
    float ev = __expf(score[n] - mx);
    acc = fmaf(ev, h[(size_t)n*HID + d], acc);
    if (d==0) esum += ev;
  }
  __shared__ float tmp[256];
  __shared__ float es[2];
  tmp[threadIdx.x] = acc;
  if (d==0) es[half] = esum;
  __syncthreads();
  if (half==0) gsum[b*HID + d] = tmp[d] + tmp[d+128];
  if (threadIdx.x==0) atomicAdd(total, es[0] + es[1]);
}

// ---------------- output mapper: one wave per graph ----------------
__global__ __launch_bounds__(64) void k_mapper(const float* __restrict__ gsum,
    const float* __restrict__ total,
    const float* __restrict__ W1, const float* __restrict__ b1,
    const float* __restrict__ g,  const float* __restrict__ bbv,
    const float* __restrict__ W2, const float* __restrict__ b2v,
    float* __restrict__ out0){
  int b = blockIdx.x, lane = threadIdx.x;
  float inv = 1.f/(*total);
  int d0 = 2*lane, d1 = d0+1;
  float gv0 = gsum[b*HID + d0]*inv, gv1 = gsum[b*HID + d1]*inv;
  float a0 = b1[d0], a1 = b1[d1];
  for (int i=0;i<HID;++i){
    float hv = lane_bcast((i&1) ? gv1 : gv0, i>>1);
    a0 = fmaf(hv, W1[i*HID + d0], a0);
    a1 = fmaf(hv, W1[i*HID + d1], a1);
  }
  a0 = fmaxf(a0, 0.f); a1 = fmaxf(a1, 0.f);
  float mu = wred_sum(a0+a1) * (1.f/HID);
  float c0 = a0-mu, c1 = a1-mu;
  float var = wred_sum(c0*c0 + c1*c1) * (1.f/HID);
  float rs = rsqrtf(var + EPS);
  float l0 = g[d0]*c0*rs + bbv[d0];
  float l1 = g[d1]*c1*rs + bbv[d1];
  float acc = b2v[lane];
  for (int j=0;j<HID;++j){
    float lv = lane_bcast((j&1) ? l1 : l0, j>>1);
    acc = fmaf(lv, W2[j*OUTD + lane], acc);
  }
  out0[b*OUTD + lane] = acc;
}

// =====================================================================
extern "C" void kernel_launch(void* const* d_in, const int* in_sizes, int n_in,
                              void* d_out, int out_size, void* d_ws, size_t ws_size,
                              hipStream_t stream){
  const float* x     = (const float*)d_in[0];
  const int*   ei    = (const int*)  d_in[1];
  const float* ea    = (const float*)d_in[2];
  const int*   batch = (const int*)  d_in[3];
  const float* encW  = (const float*)d_in[4];
  const float* encb  = (const float*)d_in[5];
  const float* encg  = (const float*)d_in[6];
  const float* encbb = (const float*)d_in[7];
  const float* gWsrc = (const float*)d_in[8];
  const float* gWdst = (const float*)d_in[9];
  const float* gWe   = (const float*)d_in[10];
  const float* gatt  = (const float*)d_in[11];
  const float* gbias = (const float*)d_in[12];
  const float* gnw   = (const float*)d_in[13];
  const float* gnb   = (const float*)d_in[14];
  const float* gns   = (const float*)d_in[15];
  const float* pW1   = (const float*)d_in[16];
  const float* pb1   = (const float*)d_in[17];
  const float* pW2   = (const float*)d_in[18];
  const float* mW1   = (const float*)d_in[19];
  const float* mb1   = (const float*)d_in[20];
  const float* mg    = (const float*)d_in[21];
  const float* mbb   = (const float*)d_in[22];
  const float* mW2   = (const float*)d_in[23];
  const float* mb2   = (const float*)d_in[24];

  char* w = (char*)d_ws;
  size_t off = 0;
  auto alloc = [&](size_t bytes)->char*{
    char* p = w + off;
    off += (bytes + 255) & ~(size_t)255;
    return p;
  };
  float*  h      = (float*) alloc((size_t)Nn*HID*4);
  float*  hs     = (float*) alloc((size_t)Nn*HID*4);
  float*  hd     = (float*) alloc((size_t)Nn*HID*4);   // hd, then GAT 'out' in place
  int*    csrc   = (int*)   alloc((size_t)E2*4);
  float2* cea    = (float2*)alloc((size_t)E2*8);
  int*    offs   = (int*)   alloc((size_t)(Nn+1)*4);
  int*    cursor = (int*)   alloc((size_t)Nn*4);
  int*    deg    = (int*)   alloc((size_t)Nn*4);
  int*    gstart = (int*)   alloc((size_t)(Bb+1)*4);
  float*  score  = (float*) alloc((size_t)Nn*4);
  float*  gsum   = (float*) alloc((size_t)Bb*HID*4);
  float*  scal   = (float*) alloc(256); // [0]=eam0 [1]=eam1 [2]=total [3]=mkey
  float*    eam   = scal;
  float*    total = scal + 2;
  unsigned* mkey  = (unsigned*)(scal + 3);

  float* out_graph = (float*)d_out;
  float* out_node  = (float*)d_out + (size_t)Bb*OUTD;

  hipMemsetAsync(deg,  0, (size_t)Nn*4, stream);
  hipMemsetAsync(scal, 0, 256, stream);

  k_encoder<<<Nn/4, 256, 0, stream>>>(x, encW, encb, encg, encbb, h);
  k_ea_mean<<<256, 256, 0, stream>>>(ea, eam);
  k_deg<<<(E2+255)/256, 256, 0, stream>>>(ei, deg);
  k_scan<<<1, 1024, 0, stream>>>(deg, offs, cursor);
  k_scatter<<<(E2+255)/256, 256, 0, stream>>>(ei, ea, eam, cursor, csrc, cea);
  k_gstart<<<(Nn+255)/256, 256, 0, stream>>>(batch, gstart);

  for (int l = 0; l < 3; ++l){
    k_dualgemm<<<512, 256, 0, stream>>>(h, gWsrc + (size_t)l*HID*HID,
                                        gWdst + (size_t)l*HID*HID, hs, hd);
    k_edge<<<Nn/4, 256, 0, stream>>>(hs, hd, h, csrc, cea, offs,
                                     gWe + (size_t)l*2*HID,
                                     gatt + (size_t)l*4*32,
                                     gbias + (size_t)l*HID);
    k_gnorm<<<Bb, 256, 0, stream>>>(hd, h, gstart,
                                    gnw + (size_t)l*HID, gnb + (size_t)l*HID,
                                    gns + (size_t)l*HID,
                                    (l==2) ? out_node : (float*)nullptr);
  }

  k_pool_score<<<512, 256, 0, stream>>>(h, pW1, pb1, pW2, score, mkey);
  k_pool_acc<<<Bb, 256, 0, stream>>>(h, score, mkey, gstart, gsum, total);
  k_mapper<<<Bb, 64, 0, stream>>>(gsum, total, mW1, mb1, mg, mbb, mW2, mb2, out_graph);
}

// Round 3
// 960.536 us; speedup vs baseline: 1.3980x; 1.3980x over previous
//
#include <hip/hip_runtime.h>
#include <hip/hip_bf16.h>

typedef __hip_bfloat16 bf16;

#define Nn   50000
#define Ee   800000
#define E2   850000
#define Bb   128
#define NFd  7
#define HID  128
#define OUTD 64
#define EPS  1e-5f
#define SLOPE 0.2f

__device__ __forceinline__ float lane_bcast(float v, int l){
  return __int_as_float(__builtin_amdgcn_readlane(__float_as_int(v), l));
}
__device__ __forceinline__ float wred_sum(float v){
  #pragma unroll
  for (int o=32;o;o>>=1) v += __shfl_xor(v, o, 64);
  return v;
}
__device__ __forceinline__ float gred16_sum(float v){
  v += __shfl_xor(v,1,64); v += __shfl_xor(v,2,64);
  v += __shfl_xor(v,4,64); v += __shfl_xor(v,8,64);
  return v;
}
__device__ __forceinline__ unsigned fkey(float f){
  unsigned u = __float_as_uint(f);
  return (u & 0x80000000u) ? ~u : (u | 0x80000000u);
}
__device__ __forceinline__ float fkeyinv(unsigned k){
  unsigned u = (k & 0x80000000u) ? (k ^ 0x80000000u) : ~k;
  return __uint_as_float(u);
}
__device__ __forceinline__ float tanh_fast(float x){
  float e = __expf(fminf(fmaxf(2.f*x, -30.f), 30.f));
  return (e-1.f)/(e+1.f);
}
__device__ __forceinline__ float bf_lo(unsigned u){ return __uint_as_float(u<<16); }
__device__ __forceinline__ float bf_hi(unsigned u){ return __uint_as_float(u & 0xffff0000u); }
__device__ __forceinline__ unsigned short f2bs(float f){
  bf16 h = __float2bfloat16(f);
  return *reinterpret_cast<unsigned short*>(&h);
}
__device__ __forceinline__ unsigned pack2(float a, float b){
  return (unsigned)f2bs(a) | ((unsigned)f2bs(b) << 16);
}

// ---------------- encoder: h = LN(ReLU(x @ W + b)) ----------------
__global__ __launch_bounds__(256) void k_encoder(
    const float* __restrict__ x, const float* __restrict__ W, const float* __restrict__ b,
    const float* __restrict__ g, const float* __restrict__ bbv, float* __restrict__ h){
  int wv = (blockIdx.x*blockDim.x + threadIdx.x) >> 6;
  if (wv >= Nn) return;
  int lane = threadIdx.x & 63;
  int d0 = 2*lane, d1 = d0+1;
  float y0 = b[d0], y1 = b[d1];
  #pragma unroll
  for (int i=0;i<NFd;++i){
    float xv = x[wv*NFd + i];
    y0 = fmaf(xv, W[i*HID + d0], y0);
    y1 = fmaf(xv, W[i*HID + d1], y1);
  }
  y0 = fmaxf(y0, 0.f); y1 = fmaxf(y1, 0.f);
  float mu = wred_sum(y0+y1) * (1.f/HID);
  float c0 = y0-mu, c1 = y1-mu;
  float var = wred_sum(c0*c0 + c1*c1) * (1.f/HID);
  float rs = rsqrtf(var + EPS);
  h[(size_t)wv*HID + d0] = g[d0]*c0*rs + bbv[d0];
  h[(size_t)wv*HID + d1] = g[d1]*c1*rs + bbv[d1];
}

// ---------------- mean of edge_attr ----------------
__global__ void k_ea_mean(const float* __restrict__ ea, float* __restrict__ eam){
  int tid = blockIdx.x*blockDim.x + threadIdx.x;
  const float2* ea2 = (const float2*)ea;
  float a0=0.f, a1=0.f;
  for (int e=tid; e<Ee; e += gridDim.x*blockDim.x){
    float2 v = ea2[e];
    a0 += v.x; a1 += v.y;
  }
  a0 = wred_sum(a0); a1 = wred_sum(a1);
  if ((threadIdx.x & 63)==0){
    atomicAdd(&eam[0], a0*(1.f/Ee));
    atomicAdd(&eam[1], a1*(1.f/Ee));
  }
}

// ---------------- CSR build ----------------
__global__ void k_deg(const int* __restrict__ ei, int* __restrict__ deg){
  int e = blockIdx.x*blockDim.x + threadIdx.x;
  if (e >= E2) return;
  int d = (e < Ee) ? ei[Ee + e] : (e - Ee);
  atomicAdd(&deg[d], 1);
}

__global__ __launch_bounds__(1024) void k_scan(const int* __restrict__ deg,
    int* __restrict__ offs, int* __restrict__ cursor){
  __shared__ int wsum[16];
  __shared__ int tot_s;
  __shared__ int carry_s;
  int t = threadIdx.x, lane = t & 63, wid = t >> 6;
  if (t==0) carry_s = 0;
  __syncthreads();
  for (int base=0; base<Nn; base += 1024){
    int i = base + t;
    int v = (i < Nn) ? deg[i] : 0;
    int x = v;
    #pragma unroll
    for (int o=1;o<64;o<<=1){ int u = __shfl_up(x, o, 64); if (lane >= o) x += u; }
    if (lane==63) wsum[wid] = x;
    __syncthreads();
    if (t==0){ int s=0; for (int k=0;k<16;++k){ int tv=wsum[k]; wsum[k]=s; s+=tv; } tot_s = s; }
    __syncthreads();
    int excl = carry_s + wsum[wid] + x - v;
    if (i < Nn){ offs[i] = excl; cursor[i] = excl; }
    __syncthreads();
    if (t==0) carry_s += tot_s;
    __syncthreads();
  }
  if (t==0) offs[Nn] = carry_s;
}

__global__ void k_scatter(const int* __restrict__ ei, const float* __restrict__ ea,
    const float* __restrict__ eam, int* __restrict__ cursor,
    int* __restrict__ csrc, float2* __restrict__ cea){
  int e = blockIdx.x*blockDim.x + threadIdx.x;
  if (e >= E2) return;
  int s, d; float a0, a1;
  if (e < Ee){
    s = ei[e]; d = ei[Ee + e];
    float2 v = ((const float2*)ea)[e];
    a0 = v.x; a1 = v.y;
  } else {
    s = d = e - Ee; a0 = eam[0]; a1 = eam[1];
  }
  int pos = atomicAdd(&cursor[d], 1);
  csrc[pos] = s;
  cea[pos] = make_float2(a0, a1);
}

// ---------------- per-graph node ranges (batch is sorted) ----------------
__global__ void k_gstart(const int* __restrict__ batch, int* __restrict__ gstart){
  int n = blockIdx.x*blockDim.x + threadIdx.x;
  if (n >= Nn) return;
  int bc = batch[n];
  int bp = (n==0) ? -1 : batch[n-1];
  for (int b = bp+1; b <= bc; ++b) gstart[b] = n;
  if (n == Nn-1){ for (int b = bc+1; b <= Bb; ++b) gstart[b] = Nn; }
}

// ---------------- hs(bf16) = h@Wsrc, hd(f32) = h@Wdst ----------------
__global__ __launch_bounds__(256) void k_dualgemm(const float* __restrict__ h,
    const float* __restrict__ Wsrc, const float* __restrict__ Wdst,
    unsigned* __restrict__ hsb, float* __restrict__ hd){
  __shared__ unsigned short wlds[HID*256];  // 64 KiB
  for (int idx = threadIdx.x; idx < HID*256/4; idx += 256){
    int r  = idx >> 6;
    int c4 = (idx & 63) * 4;
    const float* sp = (c4 < 128) ? (Wsrc + r*HID + c4) : (Wdst + r*HID + (c4-128));
    float4 v = *(const float4*)sp;
    ushort4 u;
    u.x = f2bs(v.x); u.y = f2bs(v.y); u.z = f2bs(v.z); u.w = f2bs(v.w);
    *(ushort4*)(wlds + r*256 + c4) = u;
  }
  __syncthreads();
  int wid = threadIdx.x >> 6, lane = threadIdx.x & 63;
  int nwaves = gridDim.x * 4;
  for (int p = blockIdx.x*4 + wid; p < Nn/2; p += nwaves){
    int n0 = 2*p, n1 = 2*p + 1;
    float2 h0 = *(const float2*)(h + (size_t)n0*HID + 2*lane);
    float2 h1 = *(const float2*)(h + (size_t)n1*HID + 2*lane);
    float a00=0,a01=0,a02=0,a03=0, a10=0,a11=0,a12=0,a13=0;
    #pragma unroll 8
    for (int i=0;i<HID;++i){
      float hv0 = lane_bcast((i&1) ? h0.y : h0.x, i>>1);
      float hv1 = lane_bcast((i&1) ? h1.y : h1.x, i>>1);
      uint2 wv = *(const uint2*)(wlds + i*256 + 4*lane);
      float w0=bf_lo(wv.x), w1=bf_hi(wv.x), w2=bf_lo(wv.y), w3=bf_hi(wv.y);
      a00=fmaf(hv0,w0,a00); a01=fmaf(hv0,w1,a01); a02=fmaf(hv0,w2,a02); a03=fmaf(hv0,w3,a03);
      a10=fmaf(hv1,w0,a10); a11=fmaf(hv1,w1,a11); a12=fmaf(hv1,w2,a12); a13=fmaf(hv1,w3,a13);
    }
    if (lane < 32){
      // dims 4*lane .. 4*lane+3 as packed bf16
      *(uint2*)(hsb + (size_t)n0*64 + 2*lane) = make_uint2(pack2(a00,a01), pack2(a02,a03));
      *(uint2*)(hsb + (size_t)n1*64 + 2*lane) = make_uint2(pack2(a10,a11), pack2(a12,a13));
    } else {
      *(float4*)(hd + (size_t)n0*HID + 4*lane - 128) = make_float4(a00,a01,a02,a03);
      *(float4*)(hd + (size_t)n1*HID + 4*lane - 128) = make_float4(a10,a11,a12,a13);
    }
  }
}

// ---------------- GATv2 edge aggregation: wave per dst node, online softmax -
__global__ __launch_bounds__(256) void k_edge(const unsigned* __restrict__ hsb,
    float* __restrict__ hdio, const float* __restrict__ h,
    const int* __restrict__ csrc, const float2* __restrict__ cea,
    const int* __restrict__ offs, const float* __restrict__ We,
    const float* __restrict__ att, const float* __restrict__ bias){
  int n = (blockIdx.x*blockDim.x + threadIdx.x) >> 6;
  if (n >= Nn) return;
  int lane = threadIdx.x & 63;
  int d0 = 2*lane, d1 = d0+1;
  float we00 = We[d0],       we01 = We[d1];
  float we10 = We[HID+d0],   we11 = We[HID+d1];
  float at0  = att[(lane>>4)*32 + (d0&31)];
  float at1  = att[(lane>>4)*32 + (d1&31)];
  float2 xr = *(const float2*)(hdio + (size_t)n*HID + d0);
  int e0 = offs[n], e1 = offs[n+1];
  float m = -1e30f, ssum = 0.f, acc0 = 0.f, acc1 = 0.f;
  int s_next = csrc[e0];
  float2 ea_next = cea[e0];
  for (int e = e0; e < e1; ++e){
    int s = s_next; float2 eav = ea_next;
    if (e+1 < e1){ s_next = csrc[e+1]; ea_next = cea[e+1]; }
    unsigned xlu = hsb[(size_t)s*64 + lane];
    float xl0 = bf_lo(xlu), xl1 = bf_hi(xlu);
    float z0 = fmaf(eav.y, we10, fmaf(eav.x, we00, xl0 + xr.x));
    float z1 = fmaf(eav.y, we11, fmaf(eav.x, we01, xl1 + xr.y));
    z0 = fmaxf(z0, SLOPE*z0);
    z1 = fmaxf(z1, SLOPE*z1);
    float sc = gred16_sum(fmaf(z1, at1, z0*at0));  // per-head (16-lane group) score
    float nm = fmaxf(m, sc);
    float f  = __expf(m - nm);
    float p  = __expf(sc - nm);
    ssum = ssum*f + p;
    acc0 = fmaf(p, xl0, acc0*f);
    acc1 = fmaf(p, xl1, acc1*f);
    m = nm;
  }
  float inv = 1.f/ssum;  // every node has its self-loop -> ssum > 0
  float o0 = acc0*inv + bias[d0] + h[(size_t)n*HID + d0];
  float o1 = acc1*inv + bias[d1] + h[(size_t)n*HID + d1];
  *(float2*)(hdio + (size_t)n*HID + d0) = make_float2(o0, o1);
}

// ---------------- GraphNorm reduce: per-(graph,dim) sum & sumsq ----------------
__global__ __launch_bounds__(128) void k_gn_reduce(const float* __restrict__ out,
    const int* __restrict__ gstart, float* __restrict__ gsum_, float* __restrict__ gsq_){
  int b = blockIdx.x >> 4, sub = blockIdx.x & 15;
  int ns = gstart[b], ne = gstart[b+1];
  int d = threadIdx.x;
  float s = 0.f, q = 0.f;
  for (int n = ns + sub; n < ne; n += 16){
    float v = out[(size_t)n*HID + d];
    s += v; q = fmaf(v, v, q);
  }
  atomicAdd(&gsum_[b*HID + d], s);
  atomicAdd(&gsq_[b*HID + d], q);
}

// ---------------- GraphNorm apply + ELU: wave per node ----------------
__global__ __launch_bounds__(256) void k_gn_apply(const float* __restrict__ out,
    const float* __restrict__ gsum_, const float* __restrict__ gsq_,
    const int* __restrict__ gstart, const int* __restrict__ batch,
    const float* __restrict__ gw, const float* __restrict__ gb,
    const float* __restrict__ gs, float* __restrict__ h, float* __restrict__ emb){
  int n = (blockIdx.x*blockDim.x + threadIdx.x) >> 6;
  if (n >= Nn) return;
  int lane = threadIdx.x & 63;
  int b = batch[n];
  float icnt = 1.f / fmaxf((float)(gstart[b+1]-gstart[b]), 1.f);
  int d0 = 2*lane, d1 = d0+1;
  float2 x = *(const float2*)(out + (size_t)n*HID + d0);
  float mean0 = gsum_[b*HID+d0]*icnt, mean1 = gsum_[b*HID+d1]*icnt;
  float ms0 = mean0*gs[d0], ms1 = mean1*gs[d1];
  float var0 = gsq_[b*HID+d0]*icnt - ms0*(2.f*mean0 - ms0);
  float var1 = gsq_[b*HID+d1]*icnt - ms1*(2.f*mean1 - ms1);
  float rs0 = rsqrtf(fmaxf(var0, 0.f) + EPS);
  float rs1 = rsqrtf(fmaxf(var1, 0.f) + EPS);
  float y0 = gw[d0]*(x.x - ms0)*rs0 + gb[d0];
  float y1 = gw[d1]*(x.y - ms1)*rs1 + gb[d1];
  y0 = (y0 > 0.f) ? y0 : (__expf(y0) - 1.f);
  y1 = (y1 > 0.f) ? y1 : (__expf(y1) - 1.f);
  *(float2*)(h + (size_t)n*HID + d0) = make_float2(y0, y1);
  if (emb) *(float2*)(emb + (size_t)n*HID + d0) = make_float2(y0, y1);
}

// ---------------- pooling scores + global max ----------------
__global__ __launch_bounds__(256) void k_pool_score(const float* __restrict__ h,
    const float* __restrict__ W1, const float* __restrict__ b1, const float* __restrict__ W2,
    float* __restrict__ score, unsigned* __restrict__ mkey){
  __shared__ unsigned short wlds[HID*HID];  // 32 KiB
  for (int idx = threadIdx.x; idx < HID*HID/4; idx += 256){
    float4 v = ((const float4*)W1)[idx];
    ushort4 u;
    u.x = f2bs(v.x); u.y = f2bs(v.y); u.z = f2bs(v.z); u.w = f2bs(v.w);
    ((ushort4*)wlds)[idx] = u;
  }
  __syncthreads();
  int lane = threadIdx.x & 63, wid = threadIdx.x >> 6;
  int d0 = 2*lane, d1 = d0+1;
  float bmax = -1e30f;
  for (int n = blockIdx.x*4 + wid; n < Nn; n += gridDim.x*4){
    float2 hr = *(const float2*)(h + (size_t)n*HID + d0);
    float a0 = b1[d0], a1 = b1[d1];
    #pragma unroll 8
    for (int i=0;i<HID;++i){
      float hv = lane_bcast((i&1) ? hr.y : hr.x, i>>1);
      unsigned wv = *(const unsigned*)(wlds + i*HID + d0);
      a0 = fmaf(hv, bf_lo(wv), a0);
      a1 = fmaf(hv, bf_hi(wv), a1);
    }
    float sc = tanh_fast(a0)*W2[d0] + tanh_fast(a1)*W2[d1];
    sc = wred_sum(sc);
    if (lane==0) score[n] = sc;
    bmax = fmaxf(bmax, sc);
  }
  __shared__ float bm[4];
  if (lane==0) bm[wid] = bmax;
  __syncthreads();
  if (threadIdx.x==0){
    float v = fmaxf(fmaxf(bm[0],bm[1]), fmaxf(bm[2],bm[3]));
    atomicMax(mkey, fkey(v));
  }
}

// ---------------- pooled accumulation per (graph,sub) ----------------
__global__ __launch_bounds__(128) void k_pool_reduce(const float* __restrict__ h,
    const float* __restrict__ score, const unsigned* __restrict__ mkey,
    const int* __restrict__ gstart, float* __restrict__ gsum, float* __restrict__ total){
  int b = blockIdx.x >> 4, sub = blockIdx.x & 15;
  int ns = gstart[b], ne = gstart[b+1];
  float mx = fkeyinv(*mkey);
  int d = threadIdx.x;
  float acc = 0.f, es = 0.f;
  for (int n = ns + sub; n < ne; n += 16){
    float ev = __expf(score[n] - mx);
    acc = fmaf(ev, h[(size_t)n*HID + d], acc);
    if (d==0) es += ev;
  }
  atomicAdd(&gsum[b*HID + d], acc);
  if (d==0) atomicAdd(total, es);
}

// ---------------- output mapper: one wave per graph ----------------
__global__ __launch_bounds__(64) void k_mapper(const float* __restrict__ gsum,
    const float* __restrict__ total,
    const float* __restrict__ W1, const float* __restrict__ b1,
    const float* __restrict__ g,  const float* __restrict__ bbv,
    const float* __restrict__ W2, const float* __restrict__ b2v,
    float* __restrict__ out0){
  int b = blockIdx.x, lane = threadIdx.x;
  float inv = 1.f/(*total);
  int d0 = 2*lane, d1 = d0+1;
  float gv0 = gsum[b*HID + d0]*inv, gv1 = gsum[b*HID + d1]*inv;
  float a0 = b1[d0], a1 = b1[d1];
  for (int i=0;i<HID;++i){
    float hv = lane_bcast((i&1) ? gv1 : gv0, i>>1);
    a0 = fmaf(hv, W1[i*HID + d0], a0);
    a1 = fmaf(hv, W1[i*HID + d1], a1);
  }
  a0 = fmaxf(a0, 0.f); a1 = fmaxf(a1, 0.f);
  float mu = wred_sum(a0+a1) * (1.f/HID);
  float c0 = a0-mu, c1 = a1-mu;
  float var = wred_sum(c0*c0 + c1*c1) * (1.f/HID);
  float rs = rsqrtf(var + EPS);
  float l0 = g[d0]*c0*rs + bbv[d0];
  float l1 = g[d1]*c1*rs + bbv[d1];
  float acc = b2v[lane];
  for (int j=0;j<HID;++j){
    float lv = lane_bcast((j&1) ? l1 : l0, j>>1);
    acc = fmaf(lv, W2[j*OUTD + lane], acc);
  }
  out0[b*OUTD + lane] = acc;
}

// =====================================================================
extern "C" void kernel_launch(void* const* d_in, const int* in_sizes, int n_in,
                              void* d_out, int out_size, void* d_ws, size_t ws_size,
                              hipStream_t stream){
  const float* x     = (const float*)d_in[0];
  const int*   ei    = (const int*)  d_in[1];
  const float* ea    = (const float*)d_in[2];
  const int*   batch = (const int*)  d_in[3];
  const float* encW  = (const float*)d_in[4];
  const float* encb  = (const float*)d_in[5];
  const float* encg  = (const float*)d_in[6];
  const float* encbb = (const float*)d_in[7];
  const float* gWsrc = (const float*)d_in[8];
  const float* gWdst = (const float*)d_in[9];
  const float* gWe   = (const float*)d_in[10];
  const float* gatt  = (const float*)d_in[11];
  const float* gbias = (const float*)d_in[12];
  const float* gnw   = (const float*)d_in[13];
  const float* gnb   = (const float*)d_in[14];
  const float* gns   = (const float*)d_in[15];
  const float* pW1   = (const float*)d_in[16];
  const float* pb1   = (const float*)d_in[17];
  const float* pW2   = (const float*)d_in[18];
  const float* mW1   = (const float*)d_in[19];
  const float* mb1   = (const float*)d_in[20];
  const float* mg    = (const float*)d_in[21];
  const float* mbb   = (const float*)d_in[22];
  const float* mW2   = (const float*)d_in[23];
  const float* mb2   = (const float*)d_in[24];

  char* w = (char*)d_ws;
  size_t off = 0;
  auto alloc = [&](size_t bytes)->char*{
    char* p = w + off;
    off += (bytes + 255) & ~(size_t)255;
    return p;
  };
  float*    h      = (float*)   alloc((size_t)Nn*HID*4);
  unsigned* hsb    = (unsigned*)alloc((size_t)Nn*64*4);    // bf16-packed hs
  float*    hd     = (float*)   alloc((size_t)Nn*HID*4);   // hd, then GAT 'out' in place
  int*      csrc   = (int*)     alloc((size_t)E2*4);
  float2*   cea    = (float2*)  alloc((size_t)E2*8);
  int*      offs   = (int*)     alloc((size_t)(Nn+1)*4);
  int*      cursor = (int*)     alloc((size_t)Nn*4);
  int*      deg    = (int*)     alloc((size_t)Nn*4);
  int*      gstart = (int*)     alloc((size_t)(Bb+1)*4);
  float*    score  = (float*)   alloc((size_t)Nn*4);
  float*    gsum   = (float*)   alloc((size_t)Bb*HID*4);
  float*    gnsum  = (float*)   alloc((size_t)Bb*HID*4*2); // sum | sumsq contiguous
  float*    scal   = (float*)   alloc(256); // [0]=eam0 [1]=eam1 [2]=total [3]=mkey
  float*    eam   = scal;
  float*    total = scal + 2;
  unsigned* mkey  = (unsigned*)(scal + 3);
  float*    gnsq  = gnsum + Bb*HID;

  float* out_graph = (float*)d_out;
  float* out_node  = (float*)d_out + (size_t)Bb*OUTD;

  hipMemsetAsync(deg,  0, (size_t)Nn*4, stream);
  hipMemsetAsync(scal, 0, 256, stream);
  hipMemsetAsync(gsum, 0, (size_t)Bb*HID*4, stream);

  k_encoder<<<Nn/4, 256, 0, stream>>>(x, encW, encb, encg, encbb, h);
  k_ea_mean<<<256, 256, 0, stream>>>(ea, eam);
  k_deg<<<(E2+255)/256, 256, 0, stream>>>(ei, deg);
  k_scan<<<1, 1024, 0, stream>>>(deg, offs, cursor);
  k_scatter<<<(E2+255)/256, 256, 0, stream>>>(ei, ea, eam, cursor, csrc, cea);
  k_gstart<<<(Nn+255)/256, 256, 0, stream>>>(batch, gstart);

  for (int l = 0; l < 3; ++l){
    k_dualgemm<<<512, 256, 0, stream>>>(h, gWsrc + (size_t)l*HID*HID,
                                        gWdst + (size_t)l*HID*HID, hsb, hd);
    k_edge<<<Nn/4, 256, 0, stream>>>(hsb, hd, h, csrc, cea, offs,
                                     gWe + (size_t)l*2*HID,
                                     gatt + (size_t)l*4*32,
                                     gbias + (size_t)l*HID);
    hipMemsetAsync(gnsum, 0, (size_t)Bb*HID*4*2, stream);
    k_gn_reduce<<<Bb*16, 128, 0, stream>>>(hd, gstart, gnsum, gnsq);
    k_gn_apply<<<Nn/4, 256, 0, stream>>>(hd, gnsum, gnsq, gstart, batch,
                                         gnw + (size_t)l*HID, gnb + (size_t)l*HID,
                                         gns + (size_t)l*HID, h,
                                         (l==2) ? out_node : (float*)nullptr);
  }

  k_pool_score<<<512, 256, 0, stream>>>(h, pW1, pb1, pW2, score, mkey);
  k_pool_reduce<<<Bb*16, 128, 0, stream>>>(h, score, mkey, gstart, gsum, total);
  k_mapper<<<Bb, 64, 0, stream>>>(gsum, total, mW1, mb1, mg, mbb, mW2, mb2, out_graph);
}

// Round 4
// 671.393 us; speedup vs baseline: 2.0000x; 1.4307x over previous
//
#include <hip/hip_runtime.h>
#include <hip/hip_bf16.h>

typedef __hip_bfloat16 bf16;
typedef __attribute__((ext_vector_type(8))) short short8;
typedef __attribute__((ext_vector_type(4))) float float4v;

#define Nn   50000
#define Ee   800000
#define E2   850000
#define Bb   128
#define NFd  7
#define HID  128
#define OUTD 64
#define EPS  1e-5f
#define SLOPE 0.2f
#define NSTRIP 3125          // Nn/16
#define NPAIR  1563          // ceil(NSTRIP/2)

#define MFMA16(a,b,c) __builtin_amdgcn_mfma_f32_16x16x32_bf16(a,b,c,0,0,0)

__device__ __forceinline__ float lane_bcast(float v, int l){
  return __int_as_float(__builtin_amdgcn_readlane(__float_as_int(v), l));
}
__device__ __forceinline__ float wred_sum(float v){
  #pragma unroll
  for (int o=32;o;o>>=1) v += __shfl_xor(v, o, 64);
  return v;
}
__device__ __forceinline__ float gred16_sum(float v){
  v += __shfl_xor(v,1,64); v += __shfl_xor(v,2,64);
  v += __shfl_xor(v,4,64); v += __shfl_xor(v,8,64);
  return v;
}
__device__ __forceinline__ unsigned fkey(float f){
  unsigned u = __float_as_uint(f);
  return (u & 0x80000000u) ? ~u : (u | 0x80000000u);
}
__device__ __forceinline__ float fkeyinv(unsigned k){
  unsigned u = (k & 0x80000000u) ? (k ^ 0x80000000u) : ~k;
  return __uint_as_float(u);
}
__device__ __forceinline__ float tanh_fast(float x){
  float e = __expf(fminf(fmaxf(2.f*x, -30.f), 30.f));
  return (e-1.f)/(e+1.f);
}
__device__ __forceinline__ float bf_lo(unsigned u){ return __uint_as_float(u<<16); }
__device__ __forceinline__ float bf_hi(unsigned u){ return __uint_as_float(u & 0xffff0000u); }
__device__ __forceinline__ unsigned short f2bs(float f){
  bf16 h = __float2bfloat16(f);
  return *reinterpret_cast<unsigned short*>(&h);
}
__device__ __forceinline__ unsigned pack2(float a, float b){
  return (unsigned)f2bs(a) | ((unsigned)f2bs(b) << 16);
}

// ---------------- encoder: h = LN(ReLU(x @ W + b)), + packed bf16 copy ------
__global__ __launch_bounds__(256) void k_encoder(
    const float* __restrict__ x, const float* __restrict__ W, const float* __restrict__ b,
    const float* __restrict__ g, const float* __restrict__ bbv,
    float* __restrict__ h, unsigned* __restrict__ hbu){
  int wv = (blockIdx.x*blockDim.x + threadIdx.x) >> 6;
  if (wv >= Nn) return;
  int lane = threadIdx.x & 63;
  int d0 = 2*lane, d1 = d0+1;
  float y0 = b[d0], y1 = b[d1];
  #pragma unroll
  for (int i=0;i<NFd;++i){
    float xv = x[wv*NFd + i];
    y0 = fmaf(xv, W[i*HID + d0], y0);
    y1 = fmaf(xv, W[i*HID + d1], y1);
  }
  y0 = fmaxf(y0, 0.f); y1 = fmaxf(y1, 0.f);
  float mu = wred_sum(y0+y1) * (1.f/HID);
  float c0 = y0-mu, c1 = y1-mu;
  float var = wred_sum(c0*c0 + c1*c1) * (1.f/HID);
  float rs = rsqrtf(var + EPS);
  float v0 = g[d0]*c0*rs + bbv[d0];
  float v1 = g[d1]*c1*rs + bbv[d1];
  *(float2*)(h + (size_t)wv*HID + d0) = make_float2(v0, v1);
  hbu[(size_t)wv*64 + lane] = pack2(v0, v1);
}

// ---------------- mean of edge_attr ----------------
__global__ void k_ea_mean(const float* __restrict__ ea, float* __restrict__ eam){
  int tid = blockIdx.x*blockDim.x + threadIdx.x;
  const float2* ea2 = (const float2*)ea;
  float a0=0.f, a1=0.f;
  for (int e=tid; e<Ee; e += gridDim.x*blockDim.x){
    float2 v = ea2[e];
    a0 += v.x; a1 += v.y;
  }
  a0 = wred_sum(a0); a1 = wred_sum(a1);
  if ((threadIdx.x & 63)==0){
    atomicAdd(&eam[0], a0*(1.f/Ee));
    atomicAdd(&eam[1], a1*(1.f/Ee));
  }
}

// ---------------- CSR build ----------------
__global__ void k_deg(const int* __restrict__ ei, int* __restrict__ deg){
  int e = blockIdx.x*blockDim.x + threadIdx.x;
  if (e >= E2) return;
  int d = (e < Ee) ? ei[Ee + e] : (e - Ee);
  atomicAdd(&deg[d], 1);
}

__global__ __launch_bounds__(1024) void k_scan(const int* __restrict__ deg,
    int* __restrict__ offs, int* __restrict__ cursor){
  __shared__ int wsum[16];
  __shared__ int tot_s;
  __shared__ int carry_s;
  int t = threadIdx.x, lane = t & 63, wid = t >> 6;
  if (t==0) carry_s = 0;
  __syncthreads();
  for (int base=0; base<Nn; base += 1024){
    int i = base + t;
    int v = (i < Nn) ? deg[i] : 0;
    int x = v;
    #pragma unroll
    for (int o=1;o<64;o<<=1){ int u = __shfl_up(x, o, 64); if (lane >= o) x += u; }
    if (lane==63) wsum[wid] = x;
    __syncthreads();
    if (t==0){ int s=0; for (int k=0;k<16;++k){ int tv=wsum[k]; wsum[k]=s; s+=tv; } tot_s = s; }
    __syncthreads();
    int excl = carry_s + wsum[wid] + x - v;
    if (i < Nn){ offs[i] = excl; cursor[i] = excl; }
    __syncthreads();
    if (t==0) carry_s += tot_s;
    __syncthreads();
  }
  if (t==0) offs[Nn] = carry_s;
}

__global__ void k_scatter(const int* __restrict__ ei, const float* __restrict__ ea,
    const float* __restrict__ eam, int* __restrict__ cursor,
    int* __restrict__ csrc, float2* __restrict__ cea){
  int e = blockIdx.x*blockDim.x + threadIdx.x;
  if (e >= E2) return;
  int s, d; float a0, a1;
  if (e < Ee){
    s = ei[e]; d = ei[Ee + e];
    float2 v = ((const float2*)ea)[e];
    a0 = v.x; a1 = v.y;
  } else {
    s = d = e - Ee; a0 = eam[0]; a1 = eam[1];
  }
  int pos = atomicAdd(&cursor[d], 1);
  csrc[pos] = s;
  cea[pos] = make_float2(a0, a1);
}

// ---------------- per-graph node ranges (batch is sorted) ----------------
__global__ void k_gstart(const int* __restrict__ batch, int* __restrict__ gstart){
  int n = blockIdx.x*blockDim.x + threadIdx.x;
  if (n >= Nn) return;
  int bc = batch[n];
  int bp = (n==0) ? -1 : batch[n-1];
  for (int b = bp+1; b <= bc; ++b) gstart[b] = n;
  if (n == Nn-1){ for (int b = bc+1; b <= Bb; ++b) gstart[b] = Nn; }
}

// ---------------- MFMA dual GEMM: hs(bf16)=h@Wsrc, hd(f32)=h@Wdst ----------
// D = W_T x h_T formulation: M=256 dims, N=nodes, K=128.
// LDS: W_T[256][128] bf16, XOR-swizzled (byte ^= (row&7)<<4).
__global__ __launch_bounds__(256) void k_dualgemm(
    const unsigned* __restrict__ hbu,
    const float* __restrict__ Wsrc, const float* __restrict__ Wdst,
    unsigned* __restrict__ hsb, float* __restrict__ hd){
  __shared__ unsigned short wt[256*HID];  // 64 KiB
  #pragma unroll
  for (int iter=0; iter<64; ++iter){
    int idx = iter*256 + threadIdx.x;
    int n = idx & 255, kp = idx >> 8;           // n: out-dim 0..255, kp: k-pair 0..63
    const float* Wp = (n < 128) ? Wsrc : (Wdst - 128);
    float w0 = Wp[(2*kp)*HID + n];
    float w1 = Wp[(2*kp+1)*HID + n];
    int byt = (n*256 + kp*4) ^ ((n&7)<<4);
    *(unsigned*)((char*)wt + byt) = pack2(w0, w1);
  }
  __syncthreads();
  int wid = threadIdx.x >> 6, lane = threadIdx.x & 63;
  int q = lane >> 4, c = lane & 15;
  const unsigned short* hb = (const unsigned short*)hbu;
  for (int pr = blockIdx.x*4 + wid; pr < NPAIR; pr += gridDim.x*4){
    int p0 = 2*pr, p1 = 2*pr + 1;
    bool v1 = (p1 < NSTRIP);
    int node0 = p0*16 + c;
    int node1 = v1 ? (p1*16 + c) : node0;
    short8 bf0[4], bf1[4];
    const unsigned short* hp0 = hb + (size_t)node0*HID + q*8;
    const unsigned short* hp1 = hb + (size_t)node1*HID + q*8;
    #pragma unroll
    for (int s=0;s<4;++s){
      bf0[s] = *(const short8*)(hp0 + s*32);
      bf1[s] = *(const short8*)(hp1 + s*32);
    }
    #pragma unroll 4
    for (int t=0;t<16;++t){
      float4v ac0 = {0.f,0.f,0.f,0.f}, ac1 = {0.f,0.f,0.f,0.f};
      #pragma unroll
      for (int s=0;s<4;++s){
        int row = t*16 + c;
        int byt = (row*256 + s*64 + q*16) ^ ((row&7)<<4);
        short8 af = *(const short8*)((const char*)wt + byt);
        ac0 = MFMA16(af, bf0[s], ac0);
        ac1 = MFMA16(af, bf1[s], ac1);
      }
      if (t < 8){
        int co = t*8 + q*2;   // uint index = dim/2
        *(uint2*)(hsb + (size_t)node0*64 + co) =
            make_uint2(pack2(ac0[0],ac0[1]), pack2(ac0[2],ac0[3]));
        if (v1) *(uint2*)(hsb + (size_t)node1*64 + co) =
            make_uint2(pack2(ac1[0],ac1[1]), pack2(ac1[2],ac1[3]));
      } else {
        int dd = (t-8)*16 + q*4;
        *(float4*)(hd + (size_t)node0*HID + dd) = make_float4(ac0[0],ac0[1],ac0[2],ac0[3]);
        if (v1) *(float4*)(hd + (size_t)node1*HID + dd) = make_float4(ac1[0],ac1[1],ac1[2],ac1[3]);
      }
    }
  }
}

// ---------------- GATv2 edge aggregation: wave per dst node, online softmax -
__global__ __launch_bounds__(256) void k_edge(const unsigned* __restrict__ hsb,
    float* __restrict__ hdio, const float* __restrict__ h,
    const int* __restrict__ csrc, const float2* __restrict__ cea,
    const int* __restrict__ offs, const float* __restrict__ We,
    const float* __restrict__ att, const float* __restrict__ bias){
  int n = (blockIdx.x*blockDim.x + threadIdx.x) >> 6;
  if (n >= Nn) return;
  int lane = threadIdx.x & 63;
  int d0 = 2*lane, d1 = d0+1;
  float we00 = We[d0],       we01 = We[d1];
  float we10 = We[HID+d0],   we11 = We[HID+d1];
  float at0  = att[(lane>>4)*32 + (d0&31)];
  float at1  = att[(lane>>4)*32 + (d1&31)];
  float2 xr = *(const float2*)(hdio + (size_t)n*HID + d0);
  int e0 = offs[n], e1 = offs[n+1];
  float m = -1e30f, ssum = 0.f, acc0 = 0.f, acc1 = 0.f;
  int s_next = csrc[e0];
  float2 ea_next = cea[e0];
  for (int e = e0; e < e1; ++e){
    int s = s_next; float2 eav = ea_next;
    if (e+1 < e1){ s_next = csrc[e+1]; ea_next = cea[e+1]; }
    unsigned xlu = hsb[(size_t)s*64 + lane];
    float xl0 = bf_lo(xlu), xl1 = bf_hi(xlu);
    float z0 = fmaf(eav.y, we10, fmaf(eav.x, we00, xl0 + xr.x));
    float z1 = fmaf(eav.y, we11, fmaf(eav.x, we01, xl1 + xr.y));
    z0 = fmaxf(z0, SLOPE*z0);
    z1 = fmaxf(z1, SLOPE*z1);
    float sc = gred16_sum(fmaf(z1, at1, z0*at0));  // per-head (16-lane group) score
    float nm = fmaxf(m, sc);
    float f  = __expf(m - nm);
    float p  = __expf(sc - nm);
    ssum = ssum*f + p;
    acc0 = fmaf(p, xl0, acc0*f);
    acc1 = fmaf(p, xl1, acc1*f);
    m = nm;
  }
  float inv = 1.f/ssum;  // every node has its self-loop -> ssum > 0
  float o0 = acc0*inv + bias[d0] + h[(size_t)n*HID + d0];
  float o1 = acc1*inv + bias[d1] + h[(size_t)n*HID + d1];
  *(float2*)(hdio + (size_t)n*HID + d0) = make_float2(o0, o1);
}

// ---------------- GraphNorm reduce: per-(graph,dim) sum & sumsq ----------------
__global__ __launch_bounds__(128) void k_gn_reduce(const float* __restrict__ out,
    const int* __restrict__ gstart, float* __restrict__ gsum_, float* __restrict__ gsq_){
  int b = blockIdx.x >> 4, sub = blockIdx.x & 15;
  int ns = gstart[b], ne = gstart[b+1];
  int d = threadIdx.x;
  float s = 0.f, qq = 0.f;
  for (int n = ns + sub; n < ne; n += 16){
    float v = out[(size_t)n*HID + d];
    s += v; qq = fmaf(v, v, qq);
  }
  atomicAdd(&gsum_[b*HID + d], s);
  atomicAdd(&gsq_[b*HID + d], qq);
}

// ---------------- GraphNorm apply + ELU: wave per node ----------------
__global__ __launch_bounds__(256) void k_gn_apply(const float* __restrict__ out,
    const float* __restrict__ gsum_, const float* __restrict__ gsq_,
    const int* __restrict__ gstart, const int* __restrict__ batch,
    const float* __restrict__ gw, const float* __restrict__ gb,
    const float* __restrict__ gs, float* __restrict__ h,
    unsigned* __restrict__ hbu, float* __restrict__ emb){
  int n = (blockIdx.x*blockDim.x + threadIdx.x) >> 6;
  if (n >= Nn) return;
  int lane = threadIdx.x & 63;
  int b = batch[n];
  float icnt = 1.f / fmaxf((float)(gstart[b+1]-gstart[b]), 1.f);
  int d0 = 2*lane, d1 = d0+1;
  float2 x = *(const float2*)(out + (size_t)n*HID + d0);
  float mean0 = gsum_[b*HID+d0]*icnt, mean1 = gsum_[b*HID+d1]*icnt;
  float ms0 = mean0*gs[d0], ms1 = mean1*gs[d1];
  float var0 = gsq_[b*HID+d0]*icnt - ms0*(2.f*mean0 - ms0);
  float var1 = gsq_[b*HID+d1]*icnt - ms1*(2.f*mean1 - ms1);
  float rs0 = rsqrtf(fmaxf(var0, 0.f) + EPS);
  float rs1 = rsqrtf(fmaxf(var1, 0.f) + EPS);
  float y0 = gw[d0]*(x.x - ms0)*rs0 + gb[d0];
  float y1 = gw[d1]*(x.y - ms1)*rs1 + gb[d1];
  y0 = (y0 > 0.f) ? y0 : (__expf(y0) - 1.f);
  y1 = (y1 > 0.f) ? y1 : (__expf(y1) - 1.f);
  *(float2*)(h + (size_t)n*HID + d0) = make_float2(y0, y1);
  hbu[(size_t)n*64 + lane] = pack2(y0, y1);
  if (emb) *(float2*)(emb + (size_t)n*HID + d0) = make_float2(y0, y1);
}

// ---------------- pooling scores via MFMA + global max ----------------
__global__ __launch_bounds__(256) void k_pool_score(
    const unsigned* __restrict__ hbu,
    const float* __restrict__ W1, const float* __restrict__ b1, const float* __restrict__ W2,
    float* __restrict__ score, unsigned* __restrict__ mkey){
  __shared__ unsigned short wt[HID*HID];  // 32 KiB W1_T, swizzled
  __shared__ float b1l[HID], w2l[HID];
  #pragma unroll
  for (int iter=0; iter<32; ++iter){
    int idx = iter*256 + threadIdx.x;
    int n = idx & 127, kp = idx >> 7;
    float w0 = W1[(2*kp)*HID + n];
    float w1 = W1[(2*kp+1)*HID + n];
    int byt = (n*256 + kp*4) ^ ((n&7)<<4);
    *(unsigned*)((char*)wt + byt) = pack2(w0, w1);
  }
  if (threadIdx.x < HID){ b1l[threadIdx.x] = b1[threadIdx.x]; w2l[threadIdx.x] = W2[threadIdx.x]; }
  __syncthreads();
  int wid = threadIdx.x >> 6, lane = threadIdx.x & 63;
  int q = lane >> 4, c = lane & 15;
  const unsigned short* hb = (const unsigned short*)hbu;
  float bmax = -1e30f;
  for (int p = blockIdx.x*4 + wid; p < NSTRIP; p += gridDim.x*4){
    int node = p*16 + c;
    short8 bf[4];
    const unsigned short* hp = hb + (size_t)node*HID + q*8;
    #pragma unroll
    for (int s=0;s<4;++s) bf[s] = *(const short8*)(hp + s*32);
    float part = 0.f;
    #pragma unroll
    for (int t=0;t<8;++t){
      float4v ac = {0.f,0.f,0.f,0.f};
      #pragma unroll
      for (int s=0;s<4;++s){
        int row = t*16 + c;
        int byt = (row*256 + s*64 + q*16) ^ ((row&7)<<4);
        ac = MFMA16(*(const short8*)((const char*)wt + byt), bf[s], ac);
      }
      int dim = t*16 + q*4;
      #pragma unroll
      for (int r=0;r<4;++r)
        part += tanh_fast(ac[r] + b1l[dim+r]) * w2l[dim+r];
    }
    part += __shfl_xor(part, 16, 64);
    part += __shfl_xor(part, 32, 64);
    if (q==0) score[node] = part;
    bmax = fmaxf(bmax, part);
  }
  #pragma unroll
  for (int o=32;o;o>>=1) bmax = fmaxf(bmax, __shfl_xor(bmax, o, 64));
  if (lane==0) atomicMax(mkey, fkey(bmax));
}

// ---------------- pooled accumulation per (graph,sub) ----------------
__global__ __launch_bounds__(128) void k_pool_reduce(const float* __restrict__ h,
    const float* __restrict__ score, const unsigned* __restrict__ mkey,
    const int* __restrict__ gstart, float* __restrict__ gsum, float* __restrict__ total){
  int b = blockIdx.x >> 4, sub = blockIdx.x & 15;
  int ns = gstart[b], ne = gstart[b+1];
  float mx = fkeyinv(*mkey);
  int d = threadIdx.x;
  float acc = 0.f, es = 0.f;
  for (int n = ns + sub; n < ne; n += 16){
    float ev = __expf(score[n] - mx);
    acc = fmaf(ev, h[(size_t)n*HID + d], acc);
    if (d==0) es += ev;
  }
  atomicAdd(&gsum[b*HID + d], acc);
  if (d==0) atomicAdd(total, es);
}

// ---------------- output mapper: one wave per graph ----------------
__global__ __launch_bounds__(64) void k_mapper(const float* __restrict__ gsum,
    const float* __restrict__ total,
    const float* __restrict__ W1, const float* __restrict__ b1,
    const float* __restrict__ g,  const float* __restrict__ bbv,
    const float* __restrict__ W2, const float* __restrict__ b2v,
    float* __restrict__ out0){
  int b = blockIdx.x, lane = threadIdx.x;
  float inv = 1.f/(*total);
  int d0 = 2*lane, d1 = d0+1;
  float gv0 = gsum[b*HID + d0]*inv, gv1 = gsum[b*HID + d1]*inv;
  float a0 = b1[d0], a1 = b1[d1];
  for (int i=0;i<HID;++i){
    float hv = lane_bcast((i&1) ? gv1 : gv0, i>>1);
    a0 = fmaf(hv, W1[i*HID + d0], a0);
    a1 = fmaf(hv, W1[i*HID + d1], a1);
  }
  a0 = fmaxf(a0, 0.f); a1 = fmaxf(a1, 0.f);
  float mu = wred_sum(a0+a1) * (1.f/HID);
  float c0 = a0-mu, c1 = a1-mu;
  float var = wred_sum(c0*c0 + c1*c1) * (1.f/HID);
  float rs = rsqrtf(var + EPS);
  float l0 = g[d0]*c0*rs + bbv[d0];
  float l1 = g[d1]*c1*rs + bbv[d1];
  float acc = b2v[lane];
  for (int j=0;j<HID;++j){
    float lv = lane_bcast((j&1) ? l1 : l0, j>>1);
    acc = fmaf(lv, W2[j*OUTD + lane], acc);
  }
  out0[b*OUTD + lane] = acc;
}

// =====================================================================
extern "C" void kernel_launch(void* const* d_in, const int* in_sizes, int n_in,
                              void* d_out, int out_size, void* d_ws, size_t ws_size,
                              hipStream_t stream){
  const float* x     = (const float*)d_in[0];
  const int*   ei    = (const int*)  d_in[1];
  const float* ea    = (const float*)d_in[2];
  const int*   batch = (const int*)  d_in[3];
  const float* encW  = (const float*)d_in[4];
  const float* encb  = (const float*)d_in[5];
  const float* encg  = (const float*)d_in[6];
  const float* encbb = (const float*)d_in[7];
  const float* gWsrc = (const float*)d_in[8];
  const float* gWdst = (const float*)d_in[9];
  const float* gWe   = (const float*)d_in[10];
  const float* gatt  = (const float*)d_in[11];
  const float* gbias = (const float*)d_in[12];
  const float* gnw   = (const float*)d_in[13];
  const float* gnb   = (const float*)d_in[14];
  const float* gns   = (const float*)d_in[15];
  const float* pW1   = (const float*)d_in[16];
  const float* pb1   = (const float*)d_in[17];
  const float* pW2   = (const float*)d_in[18];
  const float* mW1   = (const float*)d_in[19];
  const float* mb1   = (const float*)d_in[20];
  const float* mg    = (const float*)d_in[21];
  const float* mbb   = (const float*)d_in[22];
  const float* mW2   = (const float*)d_in[23];
  const float* mb2   = (const float*)d_in[24];

  char* w = (char*)d_ws;
  size_t off = 0;
  auto alloc = [&](size_t bytes)->char*{
    char* p = w + off;
    off += (bytes + 255) & ~(size_t)255;
    return p;
  };
  float*    h      = (float*)   alloc((size_t)Nn*HID*4);
  unsigned* hbu    = (unsigned*)alloc((size_t)Nn*64*4);    // bf16-packed h
  unsigned* hsb    = (unsigned*)alloc((size_t)Nn*64*4);    // bf16-packed hs
  float*    hd     = (float*)   alloc((size_t)Nn*HID*4);   // hd, then GAT 'out' in place
  int*      csrc   = (int*)     alloc((size_t)E2*4);
  float2*   cea    = (float2*)  alloc((size_t)E2*8);
  int*      offs   = (int*)     alloc((size_t)(Nn+1)*4);
  int*      cursor = (int*)     alloc((size_t)Nn*4);
  int*      deg    = (int*)     alloc((size_t)Nn*4);
  int*      gstart = (int*)     alloc((size_t)(Bb+1)*4);
  float*    score  = (float*)   alloc((size_t)Nn*4);
  float*    gsum   = (float*)   alloc((size_t)Bb*HID*4);
  float*    gnsum  = (float*)   alloc((size_t)Bb*HID*4*2); // sum | sumsq contiguous
  float*    scal   = (float*)   alloc(256); // [0]=eam0 [1]=eam1 [2]=total [3]=mkey
  float*    eam   = scal;
  float*    total = scal + 2;
  unsigned* mkey  = (unsigned*)(scal + 3);
  float*    gnsq  = gnsum + Bb*HID;

  float* out_graph = (float*)d_out;
  float* out_node  = (float*)d_out + (size_t)Bb*OUTD;

  hipMemsetAsync(deg,  0, (size_t)Nn*4, stream);
  hipMemsetAsync(scal, 0, 256, stream);
  hipMemsetAsync(gsum, 0, (size_t)Bb*HID*4, stream);

  k_encoder<<<Nn/4, 256, 0, stream>>>(x, encW, encb, encg, encbb, h, hbu);
  k_ea_mean<<<256, 256, 0, stream>>>(ea, eam);
  k_deg<<<(E2+255)/256, 256, 0, stream>>>(ei, deg);
  k_scan<<<1, 1024, 0, stream>>>(deg, offs, cursor);
  k_scatter<<<(E2+255)/256, 256, 0, stream>>>(ei, ea, eam, cursor, csrc, cea);
  k_gstart<<<(Nn+255)/256, 256, 0, stream>>>(batch, gstart);

  for (int l = 0; l < 3; ++l){
    k_dualgemm<<<256, 256, 0, stream>>>(hbu, gWsrc + (size_t)l*HID*HID,
                                        gWdst + (size_t)l*HID*HID, hsb, hd);
    k_edge<<<Nn/4, 256, 0, stream>>>(hsb, hd, h, csrc, cea, offs,
                                     gWe + (size_t)l*2*HID,
                                     gatt + (size_t)l*4*32,
                                     gbias + (size_t)l*HID);
    hipMemsetAsync(gnsum, 0, (size_t)Bb*HID*4*2, stream);
    k_gn_reduce<<<Bb*16, 128, 0, stream>>>(hd, gstart, gnsum, gnsq);
    k_gn_apply<<<Nn/4, 256, 0, stream>>>(hd, gnsum, gnsq, gstart, batch,
                                         gnw + (size_t)l*HID, gnb + (size_t)l*HID,
                                         gns + (size_t)l*HID, h, hbu,
                                         (l==2) ? out_node : (float*)nullptr);
  }

  k_pool_score<<<256, 256, 0, stream>>>(hbu, pW1, pb1, pW2, score, mkey);
  k_pool_reduce<<<Bb*16, 128, 0, stream>>>(h, score, mkey, gstart, gsum, total);
  k_mapper<<<Bb, 64, 0, stream>>>(gsum, total, mW1, mb1, mg, mbb, mW2, mb2, out_graph);
}

// Round 5
// 637.784 us; speedup vs baseline: 2.1054x; 1.0527x over previous
//
#include <hip/hip_runtime.h>
#include <hip/hip_bf16.h>

typedef __hip_bfloat16 bf16;
typedef __attribute__((ext_vector_type(8))) short short8;
typedef __attribute__((ext_vector_type(4))) float float4v;

#define Nn   50000
#define Ee   800000
#define E2   850000
#define Bb   128
#define NFd  7
#define HID  128
#define OUTD 64
#define EPS  1e-5f
#define SLOPE 0.2f
#define NSTRIP 3125          // Nn/16
#define NPAIR  1563          // ceil(NSTRIP/2)

#define MFMA16(a,b,c) __builtin_amdgcn_mfma_f32_16x16x32_bf16(a,b,c,0,0,0)

__device__ __forceinline__ float lane_bcast(float v, int l){
  return __int_as_float(__builtin_amdgcn_readlane(__float_as_int(v), l));
}
__device__ __forceinline__ float wred_sum(float v){
  #pragma unroll
  for (int o=32;o;o>>=1) v += __shfl_xor(v, o, 64);
  return v;
}
__device__ __forceinline__ float gred16_sum(float v){
  v += __shfl_xor(v,1,64); v += __shfl_xor(v,2,64);
  v += __shfl_xor(v,4,64); v += __shfl_xor(v,8,64);
  return v;
}
__device__ __forceinline__ unsigned fkey(float f){
  unsigned u = __float_as_uint(f);
  return (u & 0x80000000u) ? ~u : (u | 0x80000000u);
}
__device__ __forceinline__ float fkeyinv(unsigned k){
  unsigned u = (k & 0x80000000u) ? (k ^ 0x80000000u) : ~k;
  return __uint_as_float(u);
}
__device__ __forceinline__ float tanh_fast(float x){
  float e = __expf(fminf(fmaxf(2.f*x, -30.f), 30.f));
  return (e-1.f)/(e+1.f);
}
__device__ __forceinline__ float bf_lo(unsigned u){ return __uint_as_float(u<<16); }
__device__ __forceinline__ float bf_hi(unsigned u){ return __uint_as_float(u & 0xffff0000u); }
__device__ __forceinline__ unsigned short f2bs(float f){
  bf16 h = __float2bfloat16(f);
  return *reinterpret_cast<unsigned short*>(&h);
}
__device__ __forceinline__ unsigned pack2(float a, float b){
  return (unsigned)f2bs(a) | ((unsigned)f2bs(b) << 16);
}
// bijective XCD swizzle (m204): contiguous chunk per XCD
__device__ __forceinline__ int xcd_swizzle(int bid, int nwg){
  int q = nwg >> 3, r = nwg & 7;
  int x = bid & 7, i = bid >> 3;
  return (x < r ? x*(q+1) : r*(q+1) + (x-r)*q) + i;
}

// ---------------- encoder: h = LN(ReLU(x @ W + b)), + packed bf16 copy ------
__global__ __launch_bounds__(256) void k_encoder(
    const float* __restrict__ x, const float* __restrict__ W, const float* __restrict__ b,
    const float* __restrict__ g, const float* __restrict__ bbv,
    float* __restrict__ h, unsigned* __restrict__ hbu){
  int wv = (blockIdx.x*blockDim.x + threadIdx.x) >> 6;
  if (wv >= Nn) return;
  int lane = threadIdx.x & 63;
  int d0 = 2*lane, d1 = d0+1;
  float y0 = b[d0], y1 = b[d1];
  #pragma unroll
  for (int i=0;i<NFd;++i){
    float xv = x[wv*NFd + i];
    y0 = fmaf(xv, W[i*HID + d0], y0);
    y1 = fmaf(xv, W[i*HID + d1], y1);
  }
  y0 = fmaxf(y0, 0.f); y1 = fmaxf(y1, 0.f);
  float mu = wred_sum(y0+y1) * (1.f/HID);
  float c0 = y0-mu, c1 = y1-mu;
  float var = wred_sum(c0*c0 + c1*c1) * (1.f/HID);
  float rs = rsqrtf(var + EPS);
  float v0 = g[d0]*c0*rs + bbv[d0];
  float v1 = g[d1]*c1*rs + bbv[d1];
  *(float2*)(h + (size_t)wv*HID + d0) = make_float2(v0, v1);
  hbu[(size_t)wv*64 + lane] = pack2(v0, v1);
}

// ---------------- mean of edge_attr ----------------
__global__ void k_ea_mean(const float* __restrict__ ea, float* __restrict__ eam){
  int tid = blockIdx.x*blockDim.x + threadIdx.x;
  const float2* ea2 = (const float2*)ea;
  float a0=0.f, a1=0.f;
  for (int e=tid; e<Ee; e += gridDim.x*blockDim.x){
    float2 v = ea2[e];
    a0 += v.x; a1 += v.y;
  }
  a0 = wred_sum(a0); a1 = wred_sum(a1);
  if ((threadIdx.x & 63)==0){
    atomicAdd(&eam[0], a0*(1.f/Ee));
    atomicAdd(&eam[1], a1*(1.f/Ee));
  }
}

// ---------------- CSR build ----------------
__global__ void k_deg(const int* __restrict__ ei, int* __restrict__ deg){
  int e = blockIdx.x*blockDim.x + threadIdx.x;
  if (e >= E2) return;
  int d = (e < Ee) ? ei[Ee + e] : (e - Ee);
  atomicAdd(&deg[d], 1);
}

__global__ __launch_bounds__(1024) void k_scan(const int* __restrict__ deg,
    int* __restrict__ offs, int* __restrict__ cursor){
  __shared__ int wsum[16];
  __shared__ int tot_s;
  __shared__ int carry_s;
  int t = threadIdx.x, lane = t & 63, wid = t >> 6;
  if (t==0) carry_s = 0;
  __syncthreads();
  for (int base=0; base<Nn; base += 1024){
    int i = base + t;
    int v = (i < Nn) ? deg[i] : 0;
    int x = v;
    #pragma unroll
    for (int o=1;o<64;o<<=1){ int u = __shfl_up(x, o, 64); if (lane >= o) x += u; }
    if (lane==63) wsum[wid] = x;
    __syncthreads();
    if (t==0){ int s=0; for (int k=0;k<16;++k){ int tv=wsum[k]; wsum[k]=s; s+=tv; } tot_s = s; }
    __syncthreads();
    int excl = carry_s + wsum[wid] + x - v;
    if (i < Nn){ offs[i] = excl; cursor[i] = excl; }
    __syncthreads();
    if (t==0) carry_s += tot_s;
    __syncthreads();
  }
  if (t==0) offs[Nn] = carry_s;
}

__global__ void k_scatter(const int* __restrict__ ei, const float* __restrict__ ea,
    const float* __restrict__ eam, int* __restrict__ cursor,
    int* __restrict__ csrc, float2* __restrict__ cea){
  int e = blockIdx.x*blockDim.x + threadIdx.x;
  if (e >= E2) return;
  int s, d; float a0, a1;
  if (e < Ee){
    s = ei[e]; d = ei[Ee + e];
    float2 v = ((const float2*)ea)[e];
    a0 = v.x; a1 = v.y;
  } else {
    s = d = e - Ee; a0 = eam[0]; a1 = eam[1];
  }
  int pos = atomicAdd(&cursor[d], 1);
  csrc[pos] = s;
  cea[pos] = make_float2(a0, a1);
}

// ---------------- per-graph node ranges (batch is sorted) ----------------
__global__ void k_gstart(const int* __restrict__ batch, int* __restrict__ gstart){
  int n = blockIdx.x*blockDim.x + threadIdx.x;
  if (n >= Nn) return;
  int bc = batch[n];
  int bp = (n==0) ? -1 : batch[n-1];
  for (int b = bp+1; b <= bc; ++b) gstart[b] = n;
  if (n == Nn-1){ for (int b = bc+1; b <= Bb; ++b) gstart[b] = Nn; }
}

// ---------------- MFMA dual GEMM: hs(bf16)=h@Wsrc, hd(f32)=h@Wdst ----------
__global__ __launch_bounds__(256) void k_dualgemm(
    const unsigned* __restrict__ hbu,
    const float* __restrict__ Wsrc, const float* __restrict__ Wdst,
    unsigned* __restrict__ hsb, float* __restrict__ hd){
  __shared__ unsigned short wt[256*HID];  // 64 KiB
  #pragma unroll
  for (int iter=0; iter<64; ++iter){
    int idx = iter*256 + threadIdx.x;
    int n = idx & 255, kp = idx >> 8;
    const float* Wp = (n < 128) ? Wsrc : (Wdst - 128);
    float w0 = Wp[(2*kp)*HID + n];
    float w1 = Wp[(2*kp+1)*HID + n];
    int byt = (n*256 + kp*4) ^ ((n&7)<<4);
    *(unsigned*)((char*)wt + byt) = pack2(w0, w1);
  }
  __syncthreads();
  int wid = threadIdx.x >> 6, lane = threadIdx.x & 63;
  int q = lane >> 4, c = lane & 15;
  const unsigned short* hb = (const unsigned short*)hbu;
  for (int pr = blockIdx.x*4 + wid; pr < NPAIR; pr += gridDim.x*4){
    int p0 = 2*pr, p1 = 2*pr + 1;
    bool v1 = (p1 < NSTRIP);
    int node0 = p0*16 + c;
    int node1 = v1 ? (p1*16 + c) : node0;
    short8 bf0[4], bf1[4];
    const unsigned short* hp0 = hb + (size_t)node0*HID + q*8;
    const unsigned short* hp1 = hb + (size_t)node1*HID + q*8;
    #pragma unroll
    for (int s=0;s<4;++s){
      bf0[s] = *(const short8*)(hp0 + s*32);
      bf1[s] = *(const short8*)(hp1 + s*32);
    }
    #pragma unroll 4
    for (int t=0;t<16;++t){
      float4v ac0 = {0.f,0.f,0.f,0.f}, ac1 = {0.f,0.f,0.f,0.f};
      #pragma unroll
      for (int s=0;s<4;++s){
        int row = t*16 + c;
        int byt = (row*256 + s*64 + q*16) ^ ((row&7)<<4);
        short8 af = *(const short8*)((const char*)wt + byt);
        ac0 = MFMA16(af, bf0[s], ac0);
        ac1 = MFMA16(af, bf1[s], ac1);
      }
      if (t < 8){
        int co = t*8 + q*2;
        *(uint2*)(hsb + (size_t)node0*64 + co) =
            make_uint2(pack2(ac0[0],ac0[1]), pack2(ac0[2],ac0[3]));
        if (v1) *(uint2*)(hsb + (size_t)node1*64 + co) =
            make_uint2(pack2(ac1[0],ac1[1]), pack2(ac1[2],ac1[3]));
      } else {
        int dd = (t-8)*16 + q*4;
        *(float4*)(hd + (size_t)node0*HID + dd) = make_float4(ac0[0],ac0[1],ac0[2],ac0[3]);
        if (v1) *(float4*)(hd + (size_t)node1*HID + dd) = make_float4(ac1[0],ac1[1],ac1[2],ac1[3]);
      }
    }
  }
}

// ---------------- GATv2 edge aggregation: wave/node, paired online softmax --
__global__ __launch_bounds__(256) void k_edge(const unsigned* __restrict__ hsb,
    float* __restrict__ hdio, const float* __restrict__ h,
    const int* __restrict__ csrc, const float2* __restrict__ cea,
    const int* __restrict__ offs, const float* __restrict__ We,
    const float* __restrict__ att, const float* __restrict__ bias){
  int bid = xcd_swizzle(blockIdx.x, gridDim.x);
  int n = (bid*256 + (int)threadIdx.x) >> 6;
  if (n >= Nn) return;
  int lane = threadIdx.x & 63;
  int d0 = 2*lane, d1 = d0+1;
  float we00 = We[d0],       we01 = We[d1];
  float we10 = We[HID+d0],   we11 = We[HID+d1];
  float at0  = att[(lane>>4)*32 + (d0&31)];
  float at1  = att[(lane>>4)*32 + (d1&31)];
  float2 xr = *(const float2*)(hdio + (size_t)n*HID + d0);
  int e0 = offs[n], e1 = offs[n+1];
  float m = -1e30f, ssum = 0.f, acc0 = 0.f, acc1 = 0.f;

  int e = e0;
  int npair = (e1 - e0) >> 1;
  int sA, sB; float2 eA, eB; unsigned xA, xB;
  if (npair > 0){
    sA = csrc[e]; sB = csrc[e+1];
    eA = cea[e];  eB = cea[e+1];
    xA = hsb[(size_t)sA*64 + lane];
    xB = hsb[(size_t)sB*64 + lane];
  }
  for (int i = 0; i < npair; ++i){
    int sA_n=0, sB_n=0; float2 eA_n, eB_n; unsigned xA_n=0, xB_n=0;
    if (i+1 < npair){
      int en = e + 2;
      sA_n = csrc[en]; sB_n = csrc[en+1];
      eA_n = cea[en];  eB_n = cea[en+1];
      xA_n = hsb[(size_t)sA_n*64 + lane];
      xB_n = hsb[(size_t)sB_n*64 + lane];
    }
    float xA0 = bf_lo(xA), xA1 = bf_hi(xA);
    float xB0 = bf_lo(xB), xB1 = bf_hi(xB);
    float zA0 = fmaf(eA.y, we10, fmaf(eA.x, we00, xA0 + xr.x));
    float zA1 = fmaf(eA.y, we11, fmaf(eA.x, we01, xA1 + xr.y));
    float zB0 = fmaf(eB.y, we10, fmaf(eB.x, we00, xB0 + xr.x));
    float zB1 = fmaf(eB.y, we11, fmaf(eB.x, we01, xB1 + xr.y));
    zA0 = fmaxf(zA0, SLOPE*zA0); zA1 = fmaxf(zA1, SLOPE*zA1);
    zB0 = fmaxf(zB0, SLOPE*zB0); zB1 = fmaxf(zB1, SLOPE*zB1);
    float scA = gred16_sum(fmaf(zA1, at1, zA0*at0));
    float scB = gred16_sum(fmaf(zB1, at1, zB0*at0));
    float mAB = fmaxf(scA, scB);
    float nm = fmaxf(m, mAB);
    float pA = __expf(scA - nm);
    float pB = __expf(scB - nm);
    if (__any(mAB > m)){
      float f = __expf(m - nm);
      ssum = fmaf(ssum, f, pA + pB);
      acc0 = fmaf(acc0, f, fmaf(pA, xA0, pB*xB0));
      acc1 = fmaf(acc1, f, fmaf(pA, xA1, pB*xB1));
      m = nm;
    } else {
      ssum += pA + pB;
      acc0 = fmaf(pB, xB0, fmaf(pA, xA0, acc0));
      acc1 = fmaf(pB, xB1, fmaf(pA, xA1, acc1));
    }
    e += 2;
    sA=sA_n; sB=sB_n; eA=eA_n; eB=eB_n; xA=xA_n; xB=xB_n;
  }
  if (e < e1){  // odd tail
    int s = csrc[e]; float2 eav = cea[e];
    unsigned xu = hsb[(size_t)s*64 + lane];
    float x0 = bf_lo(xu), x1 = bf_hi(xu);
    float z0 = fmaf(eav.y, we10, fmaf(eav.x, we00, x0 + xr.x));
    float z1 = fmaf(eav.y, we11, fmaf(eav.x, we01, x1 + xr.y));
    z0 = fmaxf(z0, SLOPE*z0); z1 = fmaxf(z1, SLOPE*z1);
    float sc = gred16_sum(fmaf(z1, at1, z0*at0));
    float nm = fmaxf(m, sc);
    float p = __expf(sc - nm);
    if (__any(sc > m)){
      float f = __expf(m - nm);
      ssum = fmaf(ssum, f, p);
      acc0 = fmaf(acc0, f, p*x0);
      acc1 = fmaf(acc1, f, p*x1);
    } else {
      ssum += p;
      acc0 = fmaf(p, x0, acc0);
      acc1 = fmaf(p, x1, acc1);
    }
  }
  float inv = 1.f/ssum;  // every node has its self-loop -> ssum > 0
  float o0 = acc0*inv + bias[d0] + h[(size_t)n*HID + d0];
  float o1 = acc1*inv + bias[d1] + h[(size_t)n*HID + d1];
  *(float2*)(hdio + (size_t)n*HID + d0) = make_float2(o0, o1);
}

// ---------------- GraphNorm reduce: per-(graph,dim) sum & sumsq ----------------
__global__ __launch_bounds__(128) void k_gn_reduce(const float* __restrict__ out,
    const int* __restrict__ gstart, float* __restrict__ gsum_, float* __restrict__ gsq_){
  int b = blockIdx.x >> 4, sub = blockIdx.x & 15;
  int ns = gstart[b], ne = gstart[b+1];
  int d = threadIdx.x;
  float s = 0.f, qq = 0.f;
  for (int n = ns + sub; n < ne; n += 16){
    float v = out[(size_t)n*HID + d];
    s += v; qq = fmaf(v, v, qq);
  }
  atomicAdd(&gsum_[b*HID + d], s);
  atomicAdd(&gsq_[b*HID + d], qq);
}

// ---------------- GraphNorm apply + ELU: wave per node ----------------
__global__ __launch_bounds__(256) void k_gn_apply(const float* __restrict__ out,
    const float* __restrict__ gsum_, const float* __restrict__ gsq_,
    const int* __restrict__ gstart, const int* __restrict__ batch,
    const float* __restrict__ gw, const float* __restrict__ gb,
    const float* __restrict__ gs, float* __restrict__ h,
    unsigned* __restrict__ hbu, float* __restrict__ emb){
  int n = (blockIdx.x*blockDim.x + threadIdx.x) >> 6;
  if (n >= Nn) return;
  int lane = threadIdx.x & 63;
  int b = batch[n];
  float icnt = 1.f / fmaxf((float)(gstart[b+1]-gstart[b]), 1.f);
  int d0 = 2*lane, d1 = d0+1;
  float2 x = *(const float2*)(out + (size_t)n*HID + d0);
  float mean0 = gsum_[b*HID+d0]*icnt, mean1 = gsum_[b*HID+d1]*icnt;
  float ms0 = mean0*gs[d0], ms1 = mean1*gs[d1];
  float var0 = gsq_[b*HID+d0]*icnt - ms0*(2.f*mean0 - ms0);
  float var1 = gsq_[b*HID+d1]*icnt - ms1*(2.f*mean1 - ms1);
  float rs0 = rsqrtf(fmaxf(var0, 0.f) + EPS);
  float rs1 = rsqrtf(fmaxf(var1, 0.f) + EPS);
  float y0 = gw[d0]*(x.x - ms0)*rs0 + gb[d0];
  float y1 = gw[d1]*(x.y - ms1)*rs1 + gb[d1];
  y0 = (y0 > 0.f) ? y0 : (__expf(y0) - 1.f);
  y1 = (y1 > 0.f) ? y1 : (__expf(y1) - 1.f);
  *(float2*)(h + (size_t)n*HID + d0) = make_float2(y0, y1);
  hbu[(size_t)n*64 + lane] = pack2(y0, y1);
  if (emb) *(float2*)(emb + (size_t)n*HID + d0) = make_float2(y0, y1);
}

// ---------------- pooling scores via MFMA + global max ----------------
__global__ __launch_bounds__(256) void k_pool_score(
    const unsigned* __restrict__ hbu,
    const float* __restrict__ W1, const float* __restrict__ b1, const float* __restrict__ W2,
    float* __restrict__ score, unsigned* __restrict__ mkey){
  __shared__ unsigned short wt[HID*HID];  // 32 KiB W1_T, swizzled
  __shared__ float b1l[HID], w2l[HID];
  #pragma unroll
  for (int iter=0; iter<32; ++iter){
    int idx = iter*256 + threadIdx.x;
    int n = idx & 127, kp = idx >> 7;
    float w0 = W1[(2*kp)*HID + n];
    float w1 = W1[(2*kp+1)*HID + n];
    int byt = (n*256 + kp*4) ^ ((n&7)<<4);
    *(unsigned*)((char*)wt + byt) = pack2(w0, w1);
  }
  if (threadIdx.x < HID){ b1l[threadIdx.x] = b1[threadIdx.x]; w2l[threadIdx.x] = W2[threadIdx.x]; }
  __syncthreads();
  int wid = threadIdx.x >> 6, lane = threadIdx.x & 63;
  int q = lane >> 4, c = lane & 15;
  const unsigned short* hb = (const unsigned short*)hbu;
  float bmax = -1e30f;
  for (int p = blockIdx.x*4 + wid; p < NSTRIP; p += gridDim.x*4){
    int node = p*16 + c;
    short8 bf[4];
    const unsigned short* hp = hb + (size_t)node*HID + q*8;
    #pragma unroll
    for (int s=0;s<4;++s) bf[s] = *(const short8*)(hp + s*32);
    float part = 0.f;
    #pragma unroll
    for (int t=0;t<8;++t){
      float4v ac = {0.f,0.f,0.f,0.f};
      #pragma unroll
      for (int s=0;s<4;++s){
        int row = t*16 + c;
        int byt = (row*256 + s*64 + q*16) ^ ((row&7)<<4);
        ac = MFMA16(*(const short8*)((const char*)wt + byt), bf[s], ac);
      }
      int dim = t*16 + q*4;
      #pragma unroll
      for (int r=0;r<4;++r)
        part += tanh_fast(ac[r] + b1l[dim+r]) * w2l[dim+r];
    }
    part += __shfl_xor(part, 16, 64);
    part += __shfl_xor(part, 32, 64);
    if (q==0) score[node] = part;
    bmax = fmaxf(bmax, part);
  }
  #pragma unroll
  for (int o=32;o;o>>=1) bmax = fmaxf(bmax, __shfl_xor(bmax, o, 64));
  if (lane==0) atomicMax(mkey, fkey(bmax));
}

// ---------------- pooled accumulation per (graph,sub) ----------------
__global__ __launch_bounds__(128) void k_pool_reduce(const float* __restrict__ h,
    const float* __restrict__ score, const unsigned* __restrict__ mkey,
    const int* __restrict__ gstart, float* __restrict__ gsum, float* __restrict__ total){
  int b = blockIdx.x >> 4, sub = blockIdx.x & 15;
  int ns = gstart[b], ne = gstart[b+1];
  float mx = fkeyinv(*mkey);
  int d = threadIdx.x;
  float acc = 0.f, es = 0.f;
  for (int n = ns + sub; n < ne; n += 16){
    float ev = __expf(score[n] - mx);
    acc = fmaf(ev, h[(size_t)n*HID + d], acc);
    if (d==0) es += ev;
  }
  atomicAdd(&gsum[b*HID + d], acc);
  if (d==0) atomicAdd(total, es);
}

// ---------------- output mapper: one wave per graph ----------------
__global__ __launch_bounds__(64) void k_mapper(const float* __restrict__ gsum,
    const float* __restrict__ total,
    const float* __restrict__ W1, const float* __restrict__ b1,
    const float* __restrict__ g,  const float* __restrict__ bbv,
    const float* __restrict__ W2, const float* __restrict__ b2v,
    float* __restrict__ out0){
  int b = blockIdx.x, lane = threadIdx.x;
  float inv = 1.f/(*total);
  int d0 = 2*lane, d1 = d0+1;
  float gv0 = gsum[b*HID + d0]*inv, gv1 = gsum[b*HID + d1]*inv;
  float a0 = b1[d0], a1 = b1[d1];
  for (int i=0;i<HID;++i){
    float hv = lane_bcast((i&1) ? gv1 : gv0, i>>1);
    a0 = fmaf(hv, W1[i*HID + d0], a0);
    a1 = fmaf(hv, W1[i*HID + d1], a1);
  }
  a0 = fmaxf(a0, 0.f); a1 = fmaxf(a1, 0.f);
  float mu = wred_sum(a0+a1) * (1.f/HID);
  float c0 = a0-mu, c1 = a1-mu;
  float var = wred_sum(c0*c0 + c1*c1) * (1.f/HID);
  float rs = rsqrtf(var + EPS);
  float l0 = g[d0]*c0*rs + bbv[d0];
  float l1 = g[d1]*c1*rs + bbv[d1];
  float acc = b2v[lane];
  for (int j=0;j<HID;++j){
    float lv = lane_bcast((j&1) ? l1 : l0, j>>1);
    acc = fmaf(lv, W2[j*OUTD + lane], acc);
  }
  out0[b*OUTD + lane] = acc;
}

// =====================================================================
extern "C" void kernel_launch(void* const* d_in, const int* in_sizes, int n_in,
                              void* d_out, int out_size, void* d_ws, size_t ws_size,
                              hipStream_t stream){
  const float* x     = (const float*)d_in[0];
  const int*   ei    = (const int*)  d_in[1];
  const float* ea    = (const float*)d_in[2];
  const int*   batch = (const int*)  d_in[3];
  const float* encW  = (const float*)d_in[4];
  const float* encb  = (const float*)d_in[5];
  const float* encg  = (const float*)d_in[6];
  const float* encbb = (const float*)d_in[7];
  const float* gWsrc = (const float*)d_in[8];
  const float* gWdst = (const float*)d_in[9];
  const float* gWe   = (const float*)d_in[10];
  const float* gatt  = (const float*)d_in[11];
  const float* gbias = (const float*)d_in[12];
  const float* gnw   = (const float*)d_in[13];
  const float* gnb   = (const float*)d_in[14];
  const float* gns   = (const float*)d_in[15];
  const float* pW1   = (const float*)d_in[16];
  const float* pb1   = (const float*)d_in[17];
  const float* pW2   = (const float*)d_in[18];
  const float* mW1   = (const float*)d_in[19];
  const float* mb1   = (const float*)d_in[20];
  const float* mg    = (const float*)d_in[21];
  const float* mbb   = (const float*)d_in[22];
  const float* mW2   = (const float*)d_in[23];
  const float* mb2   = (const float*)d_in[24];

  char* w = (char*)d_ws;
  size_t off = 0;
  auto alloc = [&](size_t bytes)->char*{
    char* p = w + off;
    off += (bytes + 255) & ~(size_t)255;
    return p;
  };
  float*    h      = (float*)   alloc((size_t)Nn*HID*4);
  unsigned* hbu    = (unsigned*)alloc((size_t)Nn*64*4);    // bf16-packed h
  unsigned* hsb    = (unsigned*)alloc((size_t)Nn*64*4);    // bf16-packed hs
  float*    hd     = (float*)   alloc((size_t)Nn*HID*4);   // hd, then GAT 'out' in place
  int*      csrc   = (int*)     alloc((size_t)E2*4);
  float2*   cea    = (float2*)  alloc((size_t)E2*8);
  int*      offs   = (int*)     alloc((size_t)(Nn+1)*4);
  int*      cursor = (int*)     alloc((size_t)Nn*4);
  int*      deg    = (int*)     alloc((size_t)Nn*4);
  int*      gstart = (int*)     alloc((size_t)(Bb+1)*4);
  float*    score  = (float*)   alloc((size_t)Nn*4);
  float*    gsum   = (float*)   alloc((size_t)Bb*HID*4);
  float*    gnsum  = (float*)   alloc((size_t)Bb*HID*4*2); // sum | sumsq contiguous
  float*    scal   = (float*)   alloc(256); // [0]=eam0 [1]=eam1 [2]=total [3]=mkey
  float*    eam   = scal;
  float*    total = scal + 2;
  unsigned* mkey  = (unsigned*)(scal + 3);
  float*    gnsq  = gnsum + Bb*HID;

  float* out_graph = (float*)d_out;
  float* out_node  = (float*)d_out + (size_t)Bb*OUTD;

  hipMemsetAsync(deg,  0, (size_t)Nn*4, stream);
  hipMemsetAsync(scal, 0, 256, stream);
  hipMemsetAsync(gsum, 0, (size_t)Bb*HID*4, stream);

  k_encoder<<<Nn/4, 256, 0, stream>>>(x, encW, encb, encg, encbb, h, hbu);
  k_ea_mean<<<256, 256, 0, stream>>>(ea, eam);
  k_deg<<<(E2+255)/256, 256, 0, stream>>>(ei, deg);
  k_scan<<<1, 1024, 0, stream>>>(deg, offs, cursor);
  k_scatter<<<(E2+255)/256, 256, 0, stream>>>(ei, ea, eam, cursor, csrc, cea);
  k_gstart<<<(Nn+255)/256, 256, 0, stream>>>(batch, gstart);

  for (int l = 0; l < 3; ++l){
    k_dualgemm<<<256, 256, 0, stream>>>(hbu, gWsrc + (size_t)l*HID*HID,
                                        gWdst + (size_t)l*HID*HID, hsb, hd);
    k_edge<<<Nn/4, 256, 0, stream>>>(hsb, hd, h, csrc, cea, offs,
                                     gWe + (size_t)l*2*HID,
                                     gatt + (size_t)l*4*32,
                                     gbias + (size_t)l*HID);
    hipMemsetAsync(gnsum, 0, (size_t)Bb*HID*4*2, stream);
    k_gn_reduce<<<Bb*16, 128, 0, stream>>>(hd, gstart, gnsum, gnsq);
    k_gn_apply<<<Nn/4, 256, 0, stream>>>(hd, gnsum, gnsq, gstart, batch,
                                         gnw + (size_t)l*HID, gnb + (size_t)l*HID,
                                         gns + (size_t)l*HID, h, hbu,
                                         (l==2) ? out_node : (float*)nullptr);
  }

  k_pool_score<<<256, 256, 0, stream>>>(hbu, pW1, pb1, pW2, score, mkey);
  k_pool_reduce<<<Bb*16, 128, 0, stream>>>(h, score, mkey, gstart, gsum, total);
  k_mapper<<<Bb, 64, 0, stream>>>(gsum, total, mW1, mb1, mg, mbb, mW2, mb2, out_graph);
}

// Round 7
// 580.000 us; speedup vs baseline: 2.3152x; 1.0996x over previous
//
#include <hip/hip_runtime.h>
#include <hip/hip_bf16.h>

typedef __hip_bfloat16 bf16;
typedef __attribute__((ext_vector_type(8))) short short8;
typedef __attribute__((ext_vector_type(4))) float float4v;

#define Nn   50000
#define Ee   800000
#define E2   850000
#define Bb   128
#define NFd  7
#define HID  128
#define OUTD 64
#define EPS  1e-5f
#define SLOPE 0.2f
#define LOG2E 1.4426950408889634f
#define NSTRIP 3125          // Nn/16
#define NPAIR  1563          // ceil(NSTRIP/2)

#define MFMA16(a,b,c) __builtin_amdgcn_mfma_f32_16x16x32_bf16(a,b,c,0,0,0)

__device__ __forceinline__ float lane_bcast(float v, int l){
  return __int_as_float(__builtin_amdgcn_readlane(__float_as_int(v), l));
}
__device__ __forceinline__ float wred_sum(float v){
  #pragma unroll
  for (int o=32;o;o>>=1) v += __shfl_xor(v, o, 64);
  return v;
}
// full 16-lane (head-group) sum via compiler-managed DPP row-rotates:
// update_dpp -> v_mov_b32_dpp + v_add_f32 with proper hazard handling.
__device__ __forceinline__ float dpp_ror_add(float x, const int ctrl_is_below);
#define DPP_ROR_ADD(x, ctrl) \
  ((x) + __int_as_float(__builtin_amdgcn_update_dpp(0, __float_as_int(x), (ctrl), 0xf, 0xf, false)))
__device__ __forceinline__ float red16_dpp(float x){
  x = DPP_ROR_ADD(x, 0x121);  // row_ror:1
  x = DPP_ROR_ADD(x, 0x122);  // row_ror:2
  x = DPP_ROR_ADD(x, 0x124);  // row_ror:4
  x = DPP_ROR_ADD(x, 0x128);  // row_ror:8
  return x;
}
__device__ __forceinline__ unsigned fkey(float f){
  unsigned u = __float_as_uint(f);
  return (u & 0x80000000u) ? ~u : (u | 0x80000000u);
}
__device__ __forceinline__ float fkeyinv(unsigned k){
  unsigned u = (k & 0x80000000u) ? (k ^ 0x80000000u) : ~k;
  return __uint_as_float(u);
}
__device__ __forceinline__ float tanh_fast(float x){
  float e = __expf(fminf(fmaxf(2.f*x, -30.f), 30.f));
  return (e-1.f)/(e+1.f);
}
__device__ __forceinline__ float bf_lo(unsigned u){ return __uint_as_float(u<<16); }
__device__ __forceinline__ float bf_hi(unsigned u){ return __uint_as_float(u & 0xffff0000u); }
__device__ __forceinline__ unsigned short f2bs(float f){
  bf16 h = __float2bfloat16(f);
  return *reinterpret_cast<unsigned short*>(&h);
}
__device__ __forceinline__ unsigned pack2(float a, float b){
  return (unsigned)f2bs(a) | ((unsigned)f2bs(b) << 16);
}
// bijective XCD swizzle (m204): contiguous chunk per XCD
__device__ __forceinline__ int xcd_swizzle(int bid, int nwg){
  int q = nwg >> 3, r = nwg & 7;
  int x = bid & 7, i = bid >> 3;
  return (x < r ? x*(q+1) : r*(q+1) + (x-r)*q) + i;
}

// ---------------- encoder: h = LN(ReLU(x @ W + b)), + packed bf16 copy ------
__global__ __launch_bounds__(256) void k_encoder(
    const float* __restrict__ x, const float* __restrict__ W, const float* __restrict__ b,
    const float* __restrict__ g, const float* __restrict__ bbv,
    float* __restrict__ h, unsigned* __restrict__ hbu){
  int wv = (blockIdx.x*blockDim.x + threadIdx.x) >> 6;
  if (wv >= Nn) return;
  int lane = threadIdx.x & 63;
  int d0 = 2*lane, d1 = d0+1;
  float y0 = b[d0], y1 = b[d1];
  #pragma unroll
  for (int i=0;i<NFd;++i){
    float xv = x[wv*NFd + i];
    y0 = fmaf(xv, W[i*HID + d0], y0);
    y1 = fmaf(xv, W[i*HID + d1], y1);
  }
  y0 = fmaxf(y0, 0.f); y1 = fmaxf(y1, 0.f);
  float mu = wred_sum(y0+y1) * (1.f/HID);
  float c0 = y0-mu, c1 = y1-mu;
  float var = wred_sum(c0*c0 + c1*c1) * (1.f/HID);
  float rs = rsqrtf(var + EPS);
  float v0 = g[d0]*c0*rs + bbv[d0];
  float v1 = g[d1]*c1*rs + bbv[d1];
  *(float2*)(h + (size_t)wv*HID + d0) = make_float2(v0, v1);
  hbu[(size_t)wv*64 + lane] = pack2(v0, v1);
}

// ---------------- mean of edge_attr ----------------
__global__ void k_ea_mean(const float* __restrict__ ea, float* __restrict__ eam){
  int tid = blockIdx.x*blockDim.x + threadIdx.x;
  const float2* ea2 = (const float2*)ea;
  float a0=0.f, a1=0.f;
  for (int e=tid; e<Ee; e += gridDim.x*blockDim.x){
    float2 v = ea2[e];
    a0 += v.x; a1 += v.y;
  }
  a0 = wred_sum(a0); a1 = wred_sum(a1);
  if ((threadIdx.x & 63)==0){
    atomicAdd(&eam[0], a0*(1.f/Ee));
    atomicAdd(&eam[1], a1*(1.f/Ee));
  }
}

// ---------------- CSR build ----------------
__global__ void k_deg(const int* __restrict__ ei, int* __restrict__ deg){
  int e = blockIdx.x*blockDim.x + threadIdx.x;
  if (e >= E2) return;
  int d = (e < Ee) ? ei[Ee + e] : (e - Ee);
  atomicAdd(&deg[d], 1);
}

__global__ __launch_bounds__(1024) void k_scan(const int* __restrict__ deg,
    int* __restrict__ offs, int* __restrict__ cursor){
  __shared__ int wsum[16];
  __shared__ int tot_s;
  __shared__ int carry_s;
  int t = threadIdx.x, lane = t & 63, wid = t >> 6;
  if (t==0) carry_s = 0;
  __syncthreads();
  for (int base=0; base<Nn; base += 4096){
    int i0 = base + t*4;
    int v0=0,v1=0,v2=0,v3=0;
    if (i0+3 < Nn){
      int4 qv = *(const int4*)(deg + i0);
      v0=qv.x; v1=qv.y; v2=qv.z; v3=qv.w;
    } else {
      if (i0   < Nn) v0 = deg[i0];
      if (i0+1 < Nn) v1 = deg[i0+1];
      if (i0+2 < Nn) v2 = deg[i0+2];
      if (i0+3 < Nn) v3 = deg[i0+3];
    }
    int tot = v0+v1+v2+v3;
    int x = tot;
    #pragma unroll
    for (int o=1;o<64;o<<=1){ int u = __shfl_up(x, o, 64); if (lane >= o) x += u; }
    if (lane==63) wsum[wid] = x;
    __syncthreads();
    if (t==0){ int s=0; for (int k=0;k<16;++k){ int tv=wsum[k]; wsum[k]=s; s+=tv; } tot_s = s; }
    __syncthreads();
    int excl = carry_s + wsum[wid] + (x - tot);
    int p0 = excl, p1 = excl+v0, p2 = p1+v1, p3 = p2+v2;
    if (i0+3 < Nn){
      *(int4*)(offs + i0)   = make_int4(p0,p1,p2,p3);
      *(int4*)(cursor + i0) = make_int4(p0,p1,p2,p3);
    } else {
      if (i0   < Nn){ offs[i0]  =p0; cursor[i0]  =p0; }
      if (i0+1 < Nn){ offs[i0+1]=p1; cursor[i0+1]=p1; }
      if (i0+2 < Nn){ offs[i0+2]=p2; cursor[i0+2]=p2; }
      if (i0+3 < Nn){ offs[i0+3]=p3; cursor[i0+3]=p3; }
    }
    __syncthreads();
    if (t==0) carry_s += tot_s;
    __syncthreads();
  }
  if (t==0) offs[Nn] = carry_s;
}

__global__ void k_scatter(const int* __restrict__ ei, const float* __restrict__ ea,
    const float* __restrict__ eam, int* __restrict__ cursor,
    int* __restrict__ csrc, float2* __restrict__ cea){
  int e = blockIdx.x*blockDim.x + threadIdx.x;
  if (e >= E2) return;
  int s, d; float a0, a1;
  if (e < Ee){
    s = ei[e]; d = ei[Ee + e];
    float2 v = ((const float2*)ea)[e];
    a0 = v.x; a1 = v.y;
  } else {
    s = d = e - Ee; a0 = eam[0]; a1 = eam[1];
  }
  int pos = atomicAdd(&cursor[d], 1);
  csrc[pos] = s;
  cea[pos] = make_float2(a0, a1);
}

// ---------------- per-graph node ranges (batch is sorted) ----------------
__global__ void k_gstart(const int* __restrict__ batch, int* __restrict__ gstart){
  int n = blockIdx.x*blockDim.x + threadIdx.x;
  if (n >= Nn) return;
  int bc = batch[n];
  int bp = (n==0) ? -1 : batch[n-1];
  for (int b = bp+1; b <= bc; ++b) gstart[b] = n;
  if (n == Nn-1){ for (int b = bc+1; b <= Bb; ++b) gstart[b] = Nn; }
}

// ---------------- MFMA dual GEMM: hs(bf16)=h@Wsrc, hd(f32)=h@Wdst ----------
__global__ __launch_bounds__(256) void k_dualgemm(
    const unsigned* __restrict__ hbu,
    const float* __restrict__ Wsrc, const float* __restrict__ Wdst,
    unsigned* __restrict__ hsb, float* __restrict__ hd){
  __shared__ unsigned short wt[256*HID];  // 64 KiB
  #pragma unroll
  for (int iter=0; iter<64; ++iter){
    int idx = iter*256 + threadIdx.x;
    int n = idx & 255, kp = idx >> 8;
    const float* Wp = (n < 128) ? Wsrc : (Wdst - 128);
    float w0 = Wp[(2*kp)*HID + n];
    float w1 = Wp[(2*kp+1)*HID + n];
    int byt = (n*256 + kp*4) ^ ((n&7)<<4);
    *(unsigned*)((char*)wt + byt) = pack2(w0, w1);
  }
  __syncthreads();
  int wid = threadIdx.x >> 6, lane = threadIdx.x & 63;
  int q = lane >> 4, c = lane & 15;
  const unsigned short* hb = (const unsigned short*)hbu;
  for (int pr = blockIdx.x*4 + wid; pr < NPAIR; pr += gridDim.x*4){
    int p0 = 2*pr, p1 = 2*pr + 1;
    bool v1 = (p1 < NSTRIP);
    int node0 = p0*16 + c;
    int node1 = v1 ? (p1*16 + c) : node0;
    short8 bf0[4], bf1[4];
    const unsigned short* hp0 = hb + (size_t)node0*HID + q*8;
    const unsigned short* hp1 = hb + (size_t)node1*HID + q*8;
    #pragma unroll
    for (int s=0;s<4;++s){
      bf0[s] = *(const short8*)(hp0 + s*32);
      bf1[s] = *(const short8*)(hp1 + s*32);
    }
    #pragma unroll 4
    for (int t=0;t<16;++t){
      float4v ac0 = {0.f,0.f,0.f,0.f}, ac1 = {0.f,0.f,0.f,0.f};
      #pragma unroll
      for (int s=0;s<4;++s){
        int row = t*16 + c;
        int byt = (row*256 + s*64 + q*16) ^ ((row&7)<<4);
        short8 af = *(const short8*)((const char*)wt + byt);
        ac0 = MFMA16(af, bf0[s], ac0);
        ac1 = MFMA16(af, bf1[s], ac1);
      }
      if (t < 8){
        int co = t*8 + q*2;
        *(uint2*)(hsb + (size_t)node0*64 + co) =
            make_uint2(pack2(ac0[0],ac0[1]), pack2(ac0[2],ac0[3]));
        if (v1) *(uint2*)(hsb + (size_t)node1*64 + co) =
            make_uint2(pack2(ac1[0],ac1[1]), pack2(ac1[2],ac1[3]));
      } else {
        int dd = (t-8)*16 + q*4;
        *(float4*)(hd + (size_t)node0*HID + dd) = make_float4(ac0[0],ac0[1],ac0[2],ac0[3]);
        if (v1) *(float4*)(hd + (size_t)node1*HID + dd) = make_float4(ac1[0],ac1[1],ac1[2],ac1[3]);
      }
    }
  }
}

// ---------------- GATv2 edge aggregation: wave/node, fixed-offset softmax ---
// First (peeled) edge's score is the stabilizing offset m: no running max,
// no rescale, no loop-carried dependency. att pre-scaled by log2(e) -> exp2f.
__global__ __launch_bounds__(256) void k_edge(const unsigned* __restrict__ hsb,
    float* __restrict__ hdio, const float* __restrict__ h,
    const int* __restrict__ csrc, const float2* __restrict__ cea,
    const int* __restrict__ offs, const float* __restrict__ We,
    const float* __restrict__ att, const float* __restrict__ bias){
  int bid = xcd_swizzle(blockIdx.x, gridDim.x);
  int n = (bid*256 + (int)threadIdx.x) >> 6;
  if (n >= Nn) return;
  int lane = threadIdx.x & 63;
  int d0 = 2*lane, d1 = d0+1;
  float we00 = We[d0],       we01 = We[d1];
  float we10 = We[HID+d0],   we11 = We[HID+d1];
  float at0  = att[(lane>>4)*32 + (d0&31)] * LOG2E;
  float at1  = att[(lane>>4)*32 + (d1&31)] * LOG2E;
  float2 xr = *(const float2*)(hdio + (size_t)n*HID + d0);
  int e0 = offs[n], e1 = offs[n+1];

  // peel first edge (always exists: self-loop)
  unsigned xu = hsb[((unsigned)csrc[e0]<<6) + lane];
  float2 ev = cea[e0];
  float xl0 = bf_lo(xu), xl1 = bf_hi(xu);
  float z0 = fmaf(ev.y, we10, fmaf(ev.x, we00, xl0 + xr.x));
  float z1 = fmaf(ev.y, we11, fmaf(ev.x, we01, xl1 + xr.y));
  z0 = fmaxf(z0, SLOPE*z0); z1 = fmaxf(z1, SLOPE*z1);
  float m = red16_dpp(fmaf(z1, at1, z0*at0));
  float ssum = 1.f, acc0 = xl0, acc1 = xl1;

  int e = e0 + 1;
  int rem = e1 - e;
  int npair = rem >> 1;
  int sA, sB; float2 eA, eB; unsigned xA, xB;
  if (npair > 0){
    sA = csrc[e]; sB = csrc[e+1];
    eA = cea[e];  eB = cea[e+1];
    xA = hsb[((unsigned)sA<<6) + lane];
    xB = hsb[((unsigned)sB<<6) + lane];
  }
  for (int i = 0; i < npair; ++i){
    int sA_n=0, sB_n=0; float2 eA_n, eB_n; unsigned xA_n=0, xB_n=0;
    if (i+1 < npair){
      int en = e + 2;
      sA_n = csrc[en]; sB_n = csrc[en+1];
      eA_n = cea[en];  eB_n = cea[en+1];
      xA_n = hsb[((unsigned)sA_n<<6) + lane];
      xB_n = hsb[((unsigned)sB_n<<6) + lane];
    }
    float xA0 = bf_lo(xA), xA1 = bf_hi(xA);
    float xB0 = bf_lo(xB), xB1 = bf_hi(xB);
    float zA0 = fmaf(eA.y, we10, fmaf(eA.x, we00, xA0 + xr.x));
    float zA1 = fmaf(eA.y, we11, fmaf(eA.x, we01, xA1 + xr.y));
    float zB0 = fmaf(eB.y, we10, fmaf(eB.x, we00, xB0 + xr.x));
    float zB1 = fmaf(eB.y, we11, fmaf(eB.x, we01, xB1 + xr.y));
    zA0 = fmaxf(zA0, SLOPE*zA0); zA1 = fmaxf(zA1, SLOPE*zA1);
    zB0 = fmaxf(zB0, SLOPE*zB0); zB1 = fmaxf(zB1, SLOPE*zB1);
    float scA = red16_dpp(fmaf(zA1, at1, zA0*at0));
    float scB = red16_dpp(fmaf(zB1, at1, zB0*at0));
    float pA = exp2f(scA - m);
    float pB = exp2f(scB - m);
    ssum += pA + pB;
    acc0 = fmaf(pA, xA0, fmaf(pB, xB0, acc0));
    acc1 = fmaf(pA, xA1, fmaf(pB, xB1, acc1));
    e += 2;
    sA=sA_n; sB=sB_n; eA=eA_n; eB=eB_n; xA=xA_n; xB=xB_n;
  }
  if (rem & 1){  // odd tail
    int s = csrc[e1-1]; float2 eav = cea[e1-1];
    unsigned xt = hsb[((unsigned)s<<6) + lane];
    float x0 = bf_lo(xt), x1 = bf_hi(xt);
    float t0 = fmaf(eav.y, we10, fmaf(eav.x, we00, x0 + xr.x));
    float t1 = fmaf(eav.y, we11, fmaf(eav.x, we01, x1 + xr.y));
    t0 = fmaxf(t0, SLOPE*t0); t1 = fmaxf(t1, SLOPE*t1);
    float sc = red16_dpp(fmaf(t1, at1, t0*at0));
    float p = exp2f(sc - m);
    ssum += p;
    acc0 = fmaf(p, x0, acc0);
    acc1 = fmaf(p, x1, acc1);
  }
  float inv = 1.f/ssum;
  float o0 = acc0*inv + bias[d0] + h[(size_t)n*HID + d0];
  float o1 = acc1*inv + bias[d1] + h[(size_t)n*HID + d1];
  *(float2*)(hdio + (size_t)n*HID + d0) = make_float2(o0, o1);
}

// ---------------- GraphNorm reduce: per-(graph,dim) sum & sumsq ----------------
__global__ __launch_bounds__(128) void k_gn_reduce(const float* __restrict__ out,
    const int* __restrict__ gstart, float* __restrict__ gsum_, float* __restrict__ gsq_){
  int b = blockIdx.x >> 4, sub = blockIdx.x & 15;
  int ns = gstart[b], ne = gstart[b+1];
  int d = threadIdx.x;
  float s = 0.f, qq = 0.f;
  for (int n = ns + sub; n < ne; n += 16){
    float v = out[(size_t)n*HID + d];
    s += v; qq = fmaf(v, v, qq);
  }
  atomicAdd(&gsum_[b*HID + d], s);
  atomicAdd(&gsq_[b*HID + d], qq);
}

// ---------------- GraphNorm apply + ELU: wave per node ----------------
__global__ __launch_bounds__(256) void k_gn_apply(const float* __restrict__ out,
    const float* __restrict__ gsum_, const float* __restrict__ gsq_,
    const int* __restrict__ gstart, const int* __restrict__ batch,
    const float* __restrict__ gw, const float* __restrict__ gb,
    const float* __restrict__ gs, float* __restrict__ h,
    unsigned* __restrict__ hbu, float* __restrict__ emb){
  int n = (blockIdx.x*blockDim.x + threadIdx.x) >> 6;
  if (n >= Nn) return;
  int lane = threadIdx.x & 63;
  int b = batch[n];
  float icnt = 1.f / fmaxf((float)(gstart[b+1]-gstart[b]), 1.f);
  int d0 = 2*lane, d1 = d0+1;
  float2 x = *(const float2*)(out + (size_t)n*HID + d0);
  float mean0 = gsum_[b*HID+d0]*icnt, mean1 = gsum_[b*HID+d1]*icnt;
  float ms0 = mean0*gs[d0], ms1 = mean1*gs[d1];
  float var0 = gsq_[b*HID+d0]*icnt - ms0*(2.f*mean0 - ms0);
  float var1 = gsq_[b*HID+d1]*icnt - ms1*(2.f*mean1 - ms1);
  float rs0 = rsqrtf(fmaxf(var0, 0.f) + EPS);
  float rs1 = rsqrtf(fmaxf(var1, 0.f) + EPS);
  float y0 = gw[d0]*(x.x - ms0)*rs0 + gb[d0];
  float y1 = gw[d1]*(x.y - ms1)*rs1 + gb[d1];
  y0 = (y0 > 0.f) ? y0 : (__expf(y0) - 1.f);
  y1 = (y1 > 0.f) ? y1 : (__expf(y1) - 1.f);
  *(float2*)(h + (size_t)n*HID + d0) = make_float2(y0, y1);
  hbu[(size_t)n*64 + lane] = pack2(y0, y1);
  if (emb) *(float2*)(emb + (size_t)n*HID + d0) = make_float2(y0, y1);
}

// ---------------- pooling scores via MFMA + global max ----------------
__global__ __launch_bounds__(256) void k_pool_score(
    const unsigned* __restrict__ hbu,
    const float* __restrict__ W1, const float* __restrict__ b1, const float* __restrict__ W2,
    float* __restrict__ score, unsigned* __restrict__ mkey){
  __shared__ unsigned short wt[HID*HID];  // 32 KiB W1_T, swizzled
  __shared__ float b1l[HID], w2l[HID];
  #pragma unroll
  for (int iter=0; iter<32; ++iter){
    int idx = iter*256 + threadIdx.x;
    int n = idx & 127, kp = idx >> 7;
    float w0 = W1[(2*kp)*HID + n];
    float w1 = W1[(2*kp+1)*HID + n];
    int byt = (n*256 + kp*4) ^ ((n&7)<<4);
    *(unsigned*)((char*)wt + byt) = pack2(w0, w1);
  }
  if (threadIdx.x < HID){ b1l[threadIdx.x] = b1[threadIdx.x]; w2l[threadIdx.x] = W2[threadIdx.x]; }
  __syncthreads();
  int wid = threadIdx.x >> 6, lane = threadIdx.x & 63;
  int q = lane >> 4, c = lane & 15;
  const unsigned short* hb = (const unsigned short*)hbu;
  float bmax = -1e30f;
  for (int p = blockIdx.x*4 + wid; p < NSTRIP; p += gridDim.x*4){
    int node = p*16 + c;
    short8 bf[4];
    const unsigned short* hp = hb + (size_t)node*HID + q*8;
    #pragma unroll
    for (int s=0;s<4;++s) bf[s] = *(const short8*)(hp + s*32);
    float part = 0.f;
    #pragma unroll
    for (int t=0;t<8;++t){
      float4v ac = {0.f,0.f,0.f,0.f};
      #pragma unroll
      for (int s=0;s<4;++s){
        int row = t*16 + c;
        int byt = (row*256 + s*64 + q*16) ^ ((row&7)<<4);
        ac = MFMA16(*(const short8*)((const char*)wt + byt), bf[s], ac);
      }
      int dim = t*16 + q*4;
      #pragma unroll
      for (int r=0;r<4;++r)
        part += tanh_fast(ac[r] + b1l[dim+r]) * w2l[dim+r];
    }
    part += __shfl_xor(part, 16, 64);
    part += __shfl_xor(part, 32, 64);
    if (q==0) score[node] = part;
    bmax = fmaxf(bmax, part);
  }
  #pragma unroll
  for (int o=32;o;o>>=1) bmax = fmaxf(bmax, __shfl_xor(bmax, o, 64));
  if (lane==0) atomicMax(mkey, fkey(bmax));
}

// ---------------- pooled accumulation per (graph,sub) ----------------
__global__ __launch_bounds__(128) void k_pool_reduce(const float* __restrict__ h,
    const float* __restrict__ score, const unsigned* __restrict__ mkey,
    const int* __restrict__ gstart, float* __restrict__ gsum, float* __restrict__ total){
  int b = blockIdx.x >> 4, sub = blockIdx.x & 15;
  int ns = gstart[b], ne = gstart[b+1];
  float mx = fkeyinv(*mkey);
  int d = threadIdx.x;
  float acc = 0.f, es = 0.f;
  for (int n = ns + sub; n < ne; n += 16){
    float ev = __expf(score[n] - mx);
    acc = fmaf(ev, h[(size_t)n*HID + d], acc);
    if (d==0) es += ev;
  }
  atomicAdd(&gsum[b*HID + d], acc);
  if (d==0) atomicAdd(total, es);
}

// ---------------- output mapper: one wave per graph ----------------
__global__ __launch_bounds__(64) void k_mapper(const float* __restrict__ gsum,
    const float* __restrict__ total,
    const float* __restrict__ W1, const float* __restrict__ b1,
    const float* __restrict__ g,  const float* __restrict__ bbv,
    const float* __restrict__ W2, const float* __restrict__ b2v,
    float* __restrict__ out0){
  int b = blockIdx.x, lane = threadIdx.x;
  float inv = 1.f/(*total);
  int d0 = 2*lane, d1 = d0+1;
  float gv0 = gsum[b*HID + d0]*inv, gv1 = gsum[b*HID + d1]*inv;
  float a0 = b1[d0], a1 = b1[d1];
  for (int i=0;i<HID;++i){
    float hv = lane_bcast((i&1) ? gv1 : gv0, i>>1);
    a0 = fmaf(hv, W1[i*HID + d0], a0);
    a1 = fmaf(hv, W1[i*HID + d1], a1);
  }
  a0 = fmaxf(a0, 0.f); a1 = fmaxf(a1, 0.f);
  float mu = wred_sum(a0+a1) * (1.f/HID);
  float c0 = a0-mu, c1 = a1-mu;
  float var = wred_sum(c0*c0 + c1*c1) * (1.f/HID);
  float rs = rsqrtf(var + EPS);
  float l0 = g[d0]*c0*rs + bbv[d0];
  float l1 = g[d1]*c1*rs + bbv[d1];
  float acc = b2v[lane];
  for (int j=0;j<HID;++j){
    float lv = lane_bcast((j&1) ? l1 : l0, j>>1);
    acc = fmaf(lv, W2[j*OUTD + lane], acc);
  }
  out0[b*OUTD + lane] = acc;
}

// =====================================================================
extern "C" void kernel_launch(void* const* d_in, const int* in_sizes, int n_in,
                              void* d_out, int out_size, void* d_ws, size_t ws_size,
                              hipStream_t stream){
  const float* x     = (const float*)d_in[0];
  const int*   ei    = (const int*)  d_in[1];
  const float* ea    = (const float*)d_in[2];
  const int*   batch = (const int*)  d_in[3];
  const float* encW  = (const float*)d_in[4];
  const float* encb  = (const float*)d_in[5];
  const float* encg  = (const float*)d_in[6];
  const float* encbb = (const float*)d_in[7];
  const float* gWsrc = (const float*)d_in[8];
  const float* gWdst = (const float*)d_in[9];
  const float* gWe   = (const float*)d_in[10];
  const float* gatt  = (const float*)d_in[11];
  const float* gbias = (const float*)d_in[12];
  const float* gnw   = (const float*)d_in[13];
  const float* gnb   = (const float*)d_in[14];
  const float* gns   = (const float*)d_in[15];
  const float* pW1   = (const float*)d_in[16];
  const float* pb1   = (const float*)d_in[17];
  const float* pW2   = (const float*)d_in[18];
  const float* mW1   = (const float*)d_in[19];
  const float* mb1   = (const float*)d_in[20];
  const float* mg    = (const float*)d_in[21];
  const float* mbb   = (const float*)d_in[22];
  const float* mW2   = (const float*)d_in[23];
  const float* mb2   = (const float*)d_in[24];

  char* w = (char*)d_ws;
  size_t off = 0;
  auto alloc = [&](size_t bytes)->char*{
    char* p = w + off;
    off += (bytes + 255) & ~(size_t)255;
    return p;
  };
  float*    h      = (float*)   alloc((size_t)Nn*HID*4);
  unsigned* hbu    = (unsigned*)alloc((size_t)Nn*64*4);    // bf16-packed h
  unsigned* hsb    = (unsigned*)alloc((size_t)Nn*64*4);    // bf16-packed hs
  float*    hd     = (float*)   alloc((size_t)Nn*HID*4);   // hd, then GAT 'out' in place
  int*      csrc   = (int*)     alloc((size_t)E2*4);
  float2*   cea    = (float2*)  alloc((size_t)E2*8);
  int*      offs   = (int*)     alloc((size_t)(Nn+1)*4);
  int*      cursor = (int*)     alloc((size_t)Nn*4);
  int*      deg    = (int*)     alloc((size_t)Nn*4);
  int*      gstart = (int*)     alloc((size_t)(Bb+1)*4);
  float*    score  = (float*)   alloc((size_t)Nn*4);
  float*    gsum   = (float*)   alloc((size_t)Bb*HID*4);
  float*    gnsum  = (float*)   alloc((size_t)Bb*HID*4*2); // sum | sumsq contiguous
  float*    scal   = (float*)   alloc(256); // [0]=eam0 [1]=eam1 [2]=total [3]=mkey
  float*    eam   = scal;
  float*    total = scal + 2;
  unsigned* mkey  = (unsigned*)(scal + 3);
  float*    gnsq  = gnsum + Bb*HID;

  float* out_graph = (float*)d_out;
  float* out_node  = (float*)d_out + (size_t)Bb*OUTD;

  hipMemsetAsync(deg,  0, (size_t)Nn*4, stream);
  hipMemsetAsync(scal, 0, 256, stream);
  hipMemsetAsync(gsum, 0, (size_t)Bb*HID*4, stream);

  k_encoder<<<Nn/4, 256, 0, stream>>>(x, encW, encb, encg, encbb, h, hbu);
  k_ea_mean<<<256, 256, 0, stream>>>(ea, eam);
  k_deg<<<(E2+255)/256, 256, 0, stream>>>(ei, deg);
  k_scan<<<1, 1024, 0, stream>>>(deg, offs, cursor);
  k_scatter<<<(E2+255)/256, 256, 0, stream>>>(ei, ea, eam, cursor, csrc, cea);
  k_gstart<<<(Nn+255)/256, 256, 0, stream>>>(batch, gstart);

  for (int l = 0; l < 3; ++l){
    k_dualgemm<<<256, 256, 0, stream>>>(hbu, gWsrc + (size_t)l*HID*HID,
                                        gWdst + (size_t)l*HID*HID, hsb, hd);
    k_edge<<<Nn/4, 256, 0, stream>>>(hsb, hd, h, csrc, cea, offs,
                                     gWe + (size_t)l*2*HID,
                                     gatt + (size_t)l*4*32,
                                     gbias + (size_t)l*HID);
    hipMemsetAsync(gnsum, 0, (size_t)Bb*HID*4*2, stream);
    k_gn_reduce<<<Bb*16, 128, 0, stream>>>(hd, gstart, gnsum, gnsq);
    k_gn_apply<<<Nn/4, 256, 0, stream>>>(hd, gnsum, gnsq, gstart, batch,
                                         gnw + (size_t)l*HID, gnb + (size_t)l*HID,
                                         gns + (size_t)l*HID, h, hbu,
                                         (l==2) ? out_node : (float*)nullptr);
  }

  k_pool_score<<<256, 256, 0, stream>>>(hbu, pW1, pb1, pW2, score, mkey);
  k_pool_reduce<<<Bb*16, 128, 0, stream>>>(h, score, mkey, gstart, gsum, total);
  k_mapper<<<Bb, 64, 0, stream>>>(gsum, total, mW1, mb1, mg, mbb, mW2, mb2, out_graph);
}

// Round 8
// 537.461 us; speedup vs baseline: 2.4984x; 1.0791x over previous
//
#include <hip/hip_runtime.h>
#include <hip/hip_bf16.h>

typedef __hip_bfloat16 bf16;
typedef __attribute__((ext_vector_type(8))) short short8;
typedef __attribute__((ext_vector_type(4))) float float4v;

#define Nn   50000
#define Ee   800000
#define E2   850000
#define Bb   128
#define NFd  7
#define HID  128
#define OUTD 64
#define EPS  1e-5f
#define SLOPE 0.2f
#define LOG2E 1.4426950408889634f
#define NSTRIP 3125          // Nn/16
#define NPAIR  1563          // ceil(NSTRIP/2)

#define MFMA16(a,b,c) __builtin_amdgcn_mfma_f32_16x16x32_bf16(a,b,c,0,0,0)

__device__ __forceinline__ float lane_bcast(float v, int l){
  return __int_as_float(__builtin_amdgcn_readlane(__float_as_int(v), l));
}
__device__ __forceinline__ float wred_sum(float v){
  #pragma unroll
  for (int o=32;o;o>>=1) v += __shfl_xor(v, o, 64);
  return v;
}
// compiler-managed DPP helpers (hazard-safe)
#define UPD_DPP(x, ctrl) \
  __int_as_float(__builtin_amdgcn_update_dpp(0, __float_as_int(x), (ctrl), 0xf, 0xf, false))
// sum over each 4-lane quad (quad == attention head group)
__device__ __forceinline__ float red4_quad(float x){
  x = x + UPD_DPP(x, 0xB1);  // quad_perm [1,0,3,2]
  x = x + UPD_DPP(x, 0x4E);  // quad_perm [2,3,0,1]
  return x;
}
__device__ __forceinline__ unsigned fkey(float f){
  unsigned u = __float_as_uint(f);
  return (u & 0x80000000u) ? ~u : (u | 0x80000000u);
}
__device__ __forceinline__ float fkeyinv(unsigned k){
  unsigned u = (k & 0x80000000u) ? (k ^ 0x80000000u) : ~k;
  return __uint_as_float(u);
}
__device__ __forceinline__ float tanh_fast(float x){
  float e = __expf(fminf(fmaxf(2.f*x, -30.f), 30.f));
  return (e-1.f)/(e+1.f);
}
__device__ __forceinline__ float bf_lo(unsigned u){ return __uint_as_float(u<<16); }
__device__ __forceinline__ float bf_hi(unsigned u){ return __uint_as_float(u & 0xffff0000u); }
__device__ __forceinline__ unsigned short f2bs(float f){
  bf16 h = __float2bfloat16(f);
  return *reinterpret_cast<unsigned short*>(&h);
}
__device__ __forceinline__ unsigned pack2(float a, float b){
  return (unsigned)f2bs(a) | ((unsigned)f2bs(b) << 16);
}
// bijective XCD swizzle (m204): contiguous chunk per XCD
__device__ __forceinline__ int xcd_swizzle(int bid, int nwg){
  int q = nwg >> 3, r = nwg & 7;
  int x = bid & 7, i = bid >> 3;
  return (x < r ? x*(q+1) : r*(q+1) + (x-r)*q) + i;
}

// ---------------- encoder: hbu = bf16(LN(ReLU(x @ W + b))) ----------------
__global__ __launch_bounds__(256) void k_encoder(
    const float* __restrict__ x, const float* __restrict__ W, const float* __restrict__ b,
    const float* __restrict__ g, const float* __restrict__ bbv,
    unsigned* __restrict__ hbu){
  int wv = (blockIdx.x*blockDim.x + threadIdx.x) >> 6;
  if (wv >= Nn) return;
  int lane = threadIdx.x & 63;
  int d0 = 2*lane, d1 = d0+1;
  float y0 = b[d0], y1 = b[d1];
  #pragma unroll
  for (int i=0;i<NFd;++i){
    float xv = x[wv*NFd + i];
    y0 = fmaf(xv, W[i*HID + d0], y0);
    y1 = fmaf(xv, W[i*HID + d1], y1);
  }
  y0 = fmaxf(y0, 0.f); y1 = fmaxf(y1, 0.f);
  float mu = wred_sum(y0+y1) * (1.f/HID);
  float c0 = y0-mu, c1 = y1-mu;
  float var = wred_sum(c0*c0 + c1*c1) * (1.f/HID);
  float rs = rsqrtf(var + EPS);
  float v0 = g[d0]*c0*rs + bbv[d0];
  float v1 = g[d1]*c1*rs + bbv[d1];
  hbu[(size_t)wv*64 + lane] = pack2(v0, v1);
}

// ---------------- mean of edge_attr ----------------
__global__ void k_ea_mean(const float* __restrict__ ea, float* __restrict__ eam){
  int tid = blockIdx.x*blockDim.x + threadIdx.x;
  const float2* ea2 = (const float2*)ea;
  float a0=0.f, a1=0.f;
  for (int e=tid; e<Ee; e += gridDim.x*blockDim.x){
    float2 v = ea2[e];
    a0 += v.x; a1 += v.y;
  }
  a0 = wred_sum(a0); a1 = wred_sum(a1);
  if ((threadIdx.x & 63)==0){
    atomicAdd(&eam[0], a0*(1.f/Ee));
    atomicAdd(&eam[1], a1*(1.f/Ee));
  }
}

// ---------------- CSR build ----------------
__global__ void k_deg(const int* __restrict__ ei, int* __restrict__ deg){
  int e = blockIdx.x*blockDim.x + threadIdx.x;
  if (e >= E2) return;
  int d = (e < Ee) ? ei[Ee + e] : (e - Ee);
  atomicAdd(&deg[d], 1);
}

__global__ __launch_bounds__(1024) void k_scan(const int* __restrict__ deg,
    int* __restrict__ offs, int* __restrict__ cursor){
  __shared__ int wsum[16];
  __shared__ int tot_s;
  __shared__ int carry_s;
  int t = threadIdx.x, lane = t & 63, wid = t >> 6;
  if (t==0) carry_s = 0;
  __syncthreads();
  for (int base=0; base<Nn; base += 4096){
    int i0 = base + t*4;
    int v0=0,v1=0,v2=0,v3=0;
    if (i0+3 < Nn){
      int4 qv = *(const int4*)(deg + i0);
      v0=qv.x; v1=qv.y; v2=qv.z; v3=qv.w;
    } else {
      if (i0   < Nn) v0 = deg[i0];
      if (i0+1 < Nn) v1 = deg[i0+1];
      if (i0+2 < Nn) v2 = deg[i0+2];
      if (i0+3 < Nn) v3 = deg[i0+3];
    }
    int tot = v0+v1+v2+v3;
    int x = tot;
    #pragma unroll
    for (int o=1;o<64;o<<=1){ int u = __shfl_up(x, o, 64); if (lane >= o) x += u; }
    if (lane==63) wsum[wid] = x;
    __syncthreads();
    if (t==0){ int s=0; for (int k=0;k<16;++k){ int tv=wsum[k]; wsum[k]=s; s+=tv; } tot_s = s; }
    __syncthreads();
    int excl = carry_s + wsum[wid] + (x - tot);
    int p0 = excl, p1 = excl+v0, p2 = p1+v1, p3 = p2+v2;
    if (i0+3 < Nn){
      *(int4*)(offs + i0)   = make_int4(p0,p1,p2,p3);
      *(int4*)(cursor + i0) = make_int4(p0,p1,p2,p3);
    } else {
      if (i0   < Nn){ offs[i0]  =p0; cursor[i0]  =p0; }
      if (i0+1 < Nn){ offs[i0+1]=p1; cursor[i0+1]=p1; }
      if (i0+2 < Nn){ offs[i0+2]=p2; cursor[i0+2]=p2; }
      if (i0+3 < Nn){ offs[i0+3]=p3; cursor[i0+3]=p3; }
    }
    __syncthreads();
    if (t==0) carry_s += tot_s;
    __syncthreads();
  }
  if (t==0) offs[Nn] = carry_s;
}

__global__ void k_scatter(const int* __restrict__ ei, const float* __restrict__ ea,
    const float* __restrict__ eam, int* __restrict__ cursor,
    int* __restrict__ csrc, float2* __restrict__ cea){
  int e = blockIdx.x*blockDim.x + threadIdx.x;
  if (e >= E2) return;
  int s, d; float a0, a1;
  if (e < Ee){
    s = ei[e]; d = ei[Ee + e];
    float2 v = ((const float2*)ea)[e];
    a0 = v.x; a1 = v.y;
  } else {
    s = d = e - Ee; a0 = eam[0]; a1 = eam[1];
  }
  int pos = atomicAdd(&cursor[d], 1);
  csrc[pos] = s;
  cea[pos] = make_float2(a0, a1);
}

// ---------------- per-graph node ranges (batch is sorted) ----------------
__global__ void k_gstart(const int* __restrict__ batch, int* __restrict__ gstart){
  int n = blockIdx.x*blockDim.x + threadIdx.x;
  if (n >= Nn) return;
  int bc = batch[n];
  int bp = (n==0) ? -1 : batch[n-1];
  for (int b = bp+1; b <= bc; ++b) gstart[b] = n;
  if (n == Nn-1){ for (int b = bc+1; b <= Bb; ++b) gstart[b] = Nn; }
}

// ---------------- MFMA dual GEMM: hs(bf16)=h@Wsrc, hd(f32)=h@Wdst ----------
__global__ __launch_bounds__(256) void k_dualgemm(
    const unsigned* __restrict__ hbu,
    const float* __restrict__ Wsrc, const float* __restrict__ Wdst,
    unsigned* __restrict__ hsb, float* __restrict__ hd){
  __shared__ unsigned short wt[256*HID];  // 64 KiB
  #pragma unroll
  for (int iter=0; iter<64; ++iter){
    int idx = iter*256 + threadIdx.x;
    int n = idx & 255, kp = idx >> 8;
    const float* Wp = (n < 128) ? Wsrc : (Wdst - 128);
    float w0 = Wp[(2*kp)*HID + n];
    float w1 = Wp[(2*kp+1)*HID + n];
    int byt = (n*256 + kp*4) ^ ((n&7)<<4);
    *(unsigned*)((char*)wt + byt) = pack2(w0, w1);
  }
  __syncthreads();
  int wid = threadIdx.x >> 6, lane = threadIdx.x & 63;
  int q = lane >> 4, c = lane & 15;
  const unsigned short* hb = (const unsigned short*)hbu;
  for (int pr = blockIdx.x*4 + wid; pr < NPAIR; pr += gridDim.x*4){
    int p0 = 2*pr, p1 = 2*pr + 1;
    bool v1 = (p1 < NSTRIP);
    int node0 = p0*16 + c;
    int node1 = v1 ? (p1*16 + c) : node0;
    short8 bf0[4], bf1[4];
    const unsigned short* hp0 = hb + (size_t)node0*HID + q*8;
    const unsigned short* hp1 = hb + (size_t)node1*HID + q*8;
    #pragma unroll
    for (int s=0;s<4;++s){
      bf0[s] = *(const short8*)(hp0 + s*32);
      bf1[s] = *(const short8*)(hp1 + s*32);
    }
    #pragma unroll 4
    for (int t=0;t<16;++t){
      float4v ac0 = {0.f,0.f,0.f,0.f}, ac1 = {0.f,0.f,0.f,0.f};
      #pragma unroll
      for (int s=0;s<4;++s){
        int row = t*16 + c;
        int byt = (row*256 + s*64 + q*16) ^ ((row&7)<<4);
        short8 af = *(const short8*)((const char*)wt + byt);
        ac0 = MFMA16(af, bf0[s], ac0);
        ac1 = MFMA16(af, bf1[s], ac1);
      }
      if (t < 8){
        int co = t*8 + q*2;
        *(uint2*)(hsb + (size_t)node0*64 + co) =
            make_uint2(pack2(ac0[0],ac0[1]), pack2(ac0[2],ac0[3]));
        if (v1) *(uint2*)(hsb + (size_t)node1*64 + co) =
            make_uint2(pack2(ac1[0],ac1[1]), pack2(ac1[2],ac1[3]));
      } else {
        int dd = (t-8)*16 + q*4;
        *(float4*)(hd + (size_t)node0*HID + dd) = make_float4(ac0[0],ac0[1],ac0[2],ac0[3]);
        if (v1) *(float4*)(hd + (size_t)node1*HID + dd) = make_float4(ac1[0],ac1[1],ac1[2],ac1[3]);
      }
    }
  }
}

// ---------------- GATv2 edge aggregation: 4 edges/wave, 16 lanes/edge -------
// Row r (lanes 16r..16r+15) owns edge slot r; lane c owns dims 8c..8c+7
// (head = c>>2 = lane quad -> per-head score reduce = 2 quad_perm DPP adds).
// Fixed softmax offset m per (node, head) = slot-0 edge's score (iter 0).
__global__ __launch_bounds__(256) void k_edge(const unsigned* __restrict__ hsb,
    float* __restrict__ hdio, const unsigned* __restrict__ hbu,
    const int* __restrict__ csrc, const float2* __restrict__ cea,
    const int* __restrict__ offs, const float* __restrict__ We,
    const float* __restrict__ att, const float* __restrict__ bias){
  int bid = xcd_swizzle(blockIdx.x, gridDim.x);
  int n = (bid*256 + (int)threadIdx.x) >> 6;
  if (n >= Nn) return;
  int lane = threadIdx.x & 63;
  int row = lane >> 4;      // edge slot 0..3
  int c   = lane & 15;      // dim group
  int d0  = 8*c;            // dims d0..d0+7, head = c>>2
  float we0[8], we1[8], at[8], xr[8];
  #pragma unroll
  for (int j=0;j<8;++j){
    we0[j] = We[d0+j];
    we1[j] = We[HID+d0+j];
    at[j]  = att[d0+j] * LOG2E;
  }
  *(float4*)(xr)   = *(const float4*)(hdio + (size_t)n*HID + d0);
  *(float4*)(xr+4) = *(const float4*)(hdio + (size_t)n*HID + d0 + 4);
  int e0 = offs[n], e1 = offs[n+1];
  float m = 0.f, ssum = 0.f;
  float acc[8];
  #pragma unroll
  for (int j=0;j<8;++j) acc[j] = 0.f;

  // prime pipeline: group 0
  int   sC; float2 eC; uint4 xC; bool vC;
  {
    int ee = min(e0 + row, E2-1);
    vC = (e0 + row) < e1;
    sC = csrc[ee];
    eC = cea[ee];
    xC = *(const uint4*)(hsb + ((size_t)(unsigned)sC<<6) + 4*c);
  }
  for (int e = e0; e < e1; e += 4){
    int en = e + 4;
    int sN=0; float2 eN; uint4 xN; bool vN=false;
    if (en < e1){
      int ee = min(en + row, E2-1);
      vN = (en + row) < e1;
      sN = csrc[ee];
      eN = cea[ee];
      xN = *(const uint4*)(hsb + ((size_t)(unsigned)sN<<6) + 4*c);
    }
    float xl[8];
    xl[0]=bf_lo(xC.x); xl[1]=bf_hi(xC.x); xl[2]=bf_lo(xC.y); xl[3]=bf_hi(xC.y);
    xl[4]=bf_lo(xC.z); xl[5]=bf_hi(xC.z); xl[6]=bf_lo(xC.w); xl[7]=bf_hi(xC.w);
    float dot = 0.f;
    #pragma unroll
    for (int j=0;j<8;++j){
      float z = fmaf(eC.y, we1[j], fmaf(eC.x, we0[j], xl[j] + xr[j]));
      z = fmaxf(z, SLOPE*z);
      dot = fmaf(z, at[j], dot);
    }
    float sc = red4_quad(dot);          // per-(edge-slot, head) score (log2 units)
    if (e == e0) m = __shfl(sc, lane & 15, 64);  // slot-0's score per head
    float p = exp2f(sc - m);
    p = vC ? p : 0.f;
    ssum += p;
    #pragma unroll
    for (int j=0;j<8;++j) acc[j] = fmaf(p, xl[j], acc[j]);
    sC=sN; eC=eN; xC=xN; vC=vN;
  }
  // sum the 4 edge-slot rows (lane^16, lane^32 keep c -> same dims/head)
  #pragma unroll
  for (int j=0;j<8;++j){
    acc[j] += __shfl_xor(acc[j], 16, 64);
    acc[j] += __shfl_xor(acc[j], 32, 64);
  }
  ssum += __shfl_xor(ssum, 16, 64);
  ssum += __shfl_xor(ssum, 32, 64);
  if (row == 0){
    float inv = 1.f/ssum;
    uint4 hu = *(const uint4*)(hbu + ((size_t)n<<6) + 4*c);
    float hr[8];
    hr[0]=bf_lo(hu.x); hr[1]=bf_hi(hu.x); hr[2]=bf_lo(hu.y); hr[3]=bf_hi(hu.y);
    hr[4]=bf_lo(hu.z); hr[5]=bf_hi(hu.z); hr[6]=bf_lo(hu.w); hr[7]=bf_hi(hu.w);
    float o[8];
    #pragma unroll
    for (int j=0;j<8;++j) o[j] = fmaf(acc[j], inv, bias[d0+j] + hr[j]);
    *(float4*)(hdio + (size_t)n*HID + d0)     = make_float4(o[0],o[1],o[2],o[3]);
    *(float4*)(hdio + (size_t)n*HID + d0 + 4) = make_float4(o[4],o[5],o[6],o[7]);
  }
}

// ---------------- GraphNorm reduce: per-(graph,dim) sum & sumsq ----------------
__global__ __launch_bounds__(128) void k_gn_reduce(const float* __restrict__ out,
    const int* __restrict__ gstart, float* __restrict__ gsum_, float* __restrict__ gsq_){
  int b = blockIdx.x >> 4, sub = blockIdx.x & 15;
  int ns = gstart[b], ne = gstart[b+1];
  int d = threadIdx.x;
  float s = 0.f, qq = 0.f;
  for (int n = ns + sub; n < ne; n += 16){
    float v = out[(size_t)n*HID + d];
    s += v; qq = fmaf(v, v, qq);
  }
  atomicAdd(&gsum_[b*HID + d], s);
  atomicAdd(&gsq_[b*HID + d], qq);
}

// ---------------- GraphNorm apply + ELU: wave per node ----------------
__global__ __launch_bounds__(256) void k_gn_apply(const float* __restrict__ out,
    const float* __restrict__ gsum_, const float* __restrict__ gsq_,
    const int* __restrict__ gstart, const int* __restrict__ batch,
    const float* __restrict__ gw, const float* __restrict__ gb,
    const float* __restrict__ gs,
    unsigned* __restrict__ hbu, float* __restrict__ emb){
  int n = (blockIdx.x*blockDim.x + threadIdx.x) >> 6;
  if (n >= Nn) return;
  int lane = threadIdx.x & 63;
  int b = batch[n];
  float icnt = 1.f / fmaxf((float)(gstart[b+1]-gstart[b]), 1.f);
  int d0 = 2*lane, d1 = d0+1;
  float2 x = *(const float2*)(out + (size_t)n*HID + d0);
  float mean0 = gsum_[b*HID+d0]*icnt, mean1 = gsum_[b*HID+d1]*icnt;
  float ms0 = mean0*gs[d0], ms1 = mean1*gs[d1];
  float var0 = gsq_[b*HID+d0]*icnt - ms0*(2.f*mean0 - ms0);
  float var1 = gsq_[b*HID+d1]*icnt - ms1*(2.f*mean1 - ms1);
  float rs0 = rsqrtf(fmaxf(var0, 0.f) + EPS);
  float rs1 = rsqrtf(fmaxf(var1, 0.f) + EPS);
  float y0 = gw[d0]*(x.x - ms0)*rs0 + gb[d0];
  float y1 = gw[d1]*(x.y - ms1)*rs1 + gb[d1];
  y0 = (y0 > 0.f) ? y0 : (__expf(y0) - 1.f);
  y1 = (y1 > 0.f) ? y1 : (__expf(y1) - 1.f);
  hbu[(size_t)n*64 + lane] = pack2(y0, y1);
  if (emb) *(float2*)(emb + (size_t)n*HID + d0) = make_float2(y0, y1);
}

// ---------------- pooling scores via MFMA + global max ----------------
__global__ __launch_bounds__(256) void k_pool_score(
    const unsigned* __restrict__ hbu,
    const float* __restrict__ W1, const float* __restrict__ b1, const float* __restrict__ W2,
    float* __restrict__ score, unsigned* __restrict__ mkey){
  __shared__ unsigned short wt[HID*HID];  // 32 KiB W1_T, swizzled
  __shared__ float b1l[HID], w2l[HID];
  #pragma unroll
  for (int iter=0; iter<32; ++iter){
    int idx = iter*256 + threadIdx.x;
    int n = idx & 127, kp = idx >> 7;
    float w0 = W1[(2*kp)*HID + n];
    float w1 = W1[(2*kp+1)*HID + n];
    int byt = (n*256 + kp*4) ^ ((n&7)<<4);
    *(unsigned*)((char*)wt + byt) = pack2(w0, w1);
  }
  if (threadIdx.x < HID){ b1l[threadIdx.x] = b1[threadIdx.x]; w2l[threadIdx.x] = W2[threadIdx.x]; }
  __syncthreads();
  int wid = threadIdx.x >> 6, lane = threadIdx.x & 63;
  int q = lane >> 4, c = lane & 15;
  const unsigned short* hb = (const unsigned short*)hbu;
  float bmax = -1e30f;
  for (int p = blockIdx.x*4 + wid; p < NSTRIP; p += gridDim.x*4){
    int node = p*16 + c;
    short8 bf[4];
    const unsigned short* hp = hb + (size_t)node*HID + q*8;
    #pragma unroll
    for (int s=0;s<4;++s) bf[s] = *(const short8*)(hp + s*32);
    float part = 0.f;
    #pragma unroll
    for (int t=0;t<8;++t){
      float4v ac = {0.f,0.f,0.f,0.f};
      #pragma unroll
      for (int s=0;s<4;++s){
        int row = t*16 + c;
        int byt = (row*256 + s*64 + q*16) ^ ((row&7)<<4);
        ac = MFMA16(*(const short8*)((const char*)wt + byt), bf[s], ac);
      }
      int dim = t*16 + q*4;
      #pragma unroll
      for (int r=0;r<4;++r)
        part += tanh_fast(ac[r] + b1l[dim+r]) * w2l[dim+r];
    }
    part += __shfl_xor(part, 16, 64);
    part += __shfl_xor(part, 32, 64);
    if (q==0) score[node] = part;
    bmax = fmaxf(bmax, part);
  }
  #pragma unroll
  for (int o=32;o;o>>=1) bmax = fmaxf(bmax, __shfl_xor(bmax, o, 64));
  if (lane==0) atomicMax(mkey, fkey(bmax));
}

// ---------------- pooled accumulation per (graph,sub) ----------------
__global__ __launch_bounds__(128) void k_pool_reduce(const unsigned* __restrict__ hbu,
    const float* __restrict__ score, const unsigned* __restrict__ mkey,
    const int* __restrict__ gstart, float* __restrict__ gsum, float* __restrict__ total){
  int b = blockIdx.x >> 4, sub = blockIdx.x & 15;
  int ns = gstart[b], ne = gstart[b+1];
  float mx = fkeyinv(*mkey);
  int d = threadIdx.x;
  float acc = 0.f, es = 0.f;
  for (int n = ns + sub; n < ne; n += 16){
    float ev = __expf(score[n] - mx);
    unsigned u = hbu[(size_t)n*64 + (d>>1)];
    float hv = (d & 1) ? bf_hi(u) : bf_lo(u);
    acc = fmaf(ev, hv, acc);
    if (d==0) es += ev;
  }
  atomicAdd(&gsum[b*HID + d], acc);
  if (d==0) atomicAdd(total, es);
}

// ---------------- output mapper: one wave per graph ----------------
__global__ __launch_bounds__(64) void k_mapper(const float* __restrict__ gsum,
    const float* __restrict__ total,
    const float* __restrict__ W1, const float* __restrict__ b1,
    const float* __restrict__ g,  const float* __restrict__ bbv,
    const float* __restrict__ W2, const float* __restrict__ b2v,
    float* __restrict__ out0){
  int b = blockIdx.x, lane = threadIdx.x;
  float inv = 1.f/(*total);
  int d0 = 2*lane, d1 = d0+1;
  float gv0 = gsum[b*HID + d0]*inv, gv1 = gsum[b*HID + d1]*inv;
  float a0 = b1[d0], a1 = b1[d1];
  for (int i=0;i<HID;++i){
    float hv = lane_bcast((i&1) ? gv1 : gv0, i>>1);
    a0 = fmaf(hv, W1[i*HID + d0], a0);
    a1 = fmaf(hv, W1[i*HID + d1], a1);
  }
  a0 = fmaxf(a0, 0.f); a1 = fmaxf(a1, 0.f);
  float mu = wred_sum(a0+a1) * (1.f/HID);
  float c0 = a0-mu, c1 = a1-mu;
  float var = wred_sum(c0*c0 + c1*c1) * (1.f/HID);
  float rs = rsqrtf(var + EPS);
  float l0 = g[d0]*c0*rs + bbv[d0];
  float l1 = g[d1]*c1*rs + bbv[d1];
  float acc = b2v[lane];
  for (int j=0;j<HID;++j){
    float lv = lane_bcast((j&1) ? l1 : l0, j>>1);
    acc = fmaf(lv, W2[j*OUTD + lane], acc);
  }
  out0[b*OUTD + lane] = acc;
}

// =====================================================================
extern "C" void kernel_launch(void* const* d_in, const int* in_sizes, int n_in,
                              void* d_out, int out_size, void* d_ws, size_t ws_size,
                              hipStream_t stream){
  const float* x     = (const float*)d_in[0];
  const int*   ei    = (const int*)  d_in[1];
  const float* ea    = (const float*)d_in[2];
  const int*   batch = (const int*)  d_in[3];
  const float* encW  = (const float*)d_in[4];
  const float* encb  = (const float*)d_in[5];
  const float* encg  = (const float*)d_in[6];
  const float* encbb = (const float*)d_in[7];
  const float* gWsrc = (const float*)d_in[8];
  const float* gWdst = (const float*)d_in[9];
  const float* gWe   = (const float*)d_in[10];
  const float* gatt  = (const float*)d_in[11];
  const float* gbias = (const float*)d_in[12];
  const float* gnw   = (const float*)d_in[13];
  const float* gnb   = (const float*)d_in[14];
  const float* gns   = (const float*)d_in[15];
  const float* pW1   = (const float*)d_in[16];
  const float* pb1   = (const float*)d_in[17];
  const float* pW2   = (const float*)d_in[18];
  const float* mW1   = (const float*)d_in[19];
  const float* mb1   = (const float*)d_in[20];
  const float* mg    = (const float*)d_in[21];
  const float* mbb   = (const float*)d_in[22];
  const float* mW2   = (const float*)d_in[23];
  const float* mb2   = (const float*)d_in[24];

  char* w = (char*)d_ws;
  size_t off = 0;
  auto alloc = [&](size_t bytes)->char*{
    char* p = w + off;
    off += (bytes + 255) & ~(size_t)255;
    return p;
  };
  unsigned* hbu    = (unsigned*)alloc((size_t)Nn*64*4);    // bf16-packed h
  unsigned* hsb    = (unsigned*)alloc((size_t)Nn*64*4);    // bf16-packed hs
  float*    hd     = (float*)   alloc((size_t)Nn*HID*4);   // hd, then GAT 'out' in place
  int*      csrc   = (int*)     alloc((size_t)E2*4);
  float2*   cea    = (float2*)  alloc((size_t)E2*8);
  int*      offs   = (int*)     alloc((size_t)(Nn+1)*4);
  int*      cursor = (int*)     alloc((size_t)Nn*4);
  int*      deg    = (int*)     alloc((size_t)Nn*4);
  int*      gstart = (int*)     alloc((size_t)(Bb+1)*4);
  float*    score  = (float*)   alloc((size_t)Nn*4);
  float*    gsum   = (float*)   alloc((size_t)Bb*HID*4);
  float*    gnsum  = (float*)   alloc((size_t)Bb*HID*4*2); // sum | sumsq contiguous
  float*    scal   = (float*)   alloc(256); // [0]=eam0 [1]=eam1 [2]=total [3]=mkey
  float*    eam   = scal;
  float*    total = scal + 2;
  unsigned* mkey  = (unsigned*)(scal + 3);
  float*    gnsq  = gnsum + Bb*HID;

  float* out_graph = (float*)d_out;
  float* out_node  = (float*)d_out + (size_t)Bb*OUTD;

  hipMemsetAsync(deg,  0, (size_t)Nn*4, stream);
  hipMemsetAsync(scal, 0, 256, stream);
  hipMemsetAsync(gsum, 0, (size_t)Bb*HID*4, stream);

  k_encoder<<<Nn/4, 256, 0, stream>>>(x, encW, encb, encg, encbb, hbu);
  k_ea_mean<<<256, 256, 0, stream>>>(ea, eam);
  k_deg<<<(E2+255)/256, 256, 0, stream>>>(ei, deg);
  k_scan<<<1, 1024, 0, stream>>>(deg, offs, cursor);
  k_scatter<<<(E2+255)/256, 256, 0, stream>>>(ei, ea, eam, cursor, csrc, cea);
  k_gstart<<<(Nn+255)/256, 256, 0, stream>>>(batch, gstart);

  for (int l = 0; l < 3; ++l){
    k_dualgemm<<<512, 256, 0, stream>>>(hbu, gWsrc + (size_t)l*HID*HID,
                                        gWdst + (size_t)l*HID*HID, hsb, hd);
    k_edge<<<Nn/4, 256, 0, stream>>>(hsb, hd, hbu, csrc, cea, offs,
                                     gWe + (size_t)l*2*HID,
                                     gatt + (size_t)l*4*32,
                                     gbias + (size_t)l*HID);
    hipMemsetAsync(gnsum, 0, (size_t)Bb*HID*4*2, stream);
    k_gn_reduce<<<Bb*16, 128, 0, stream>>>(hd, gstart, gnsum, gnsq);
    k_gn_apply<<<Nn/4, 256, 0, stream>>>(hd, gnsum, gnsq, gstart, batch,
                                         gnw + (size_t)l*HID, gnb + (size_t)l*HID,
                                         gns + (size_t)l*HID, hbu,
                                         (l==2) ? out_node : (float*)nullptr);
  }

  k_pool_score<<<256, 256, 0, stream>>>(hbu, pW1, pb1, pW2, score, mkey);
  k_pool_reduce<<<Bb*16, 128, 0, stream>>>(hbu, score, mkey, gstart, gsum, total);
  k_mapper<<<Bb, 64, 0, stream>>>(gsum, total, mW1, mb1, mg, mbb, mW2, mb2, out_graph);
}